// Round 10
// baseline (1288.644 us; speedup 1.0000x reference)
//
#include <hip/hip_runtime.h>
#include <hip/hip_bf16.h>

#define NN 30000
#define NE 480000
#define NH 4
#define DH 64
#define MF 30
#define KG 10
#define RATIO 0.18257418583505536f   /* 1/sqrt(30) */
#define DNRM  0.35355339059327373f   /* 64^-0.25  */

// fp32 params block layout (element offsets)
#define P_WF    0        /* [768][256] Wq|Wk|Wv rows */
#define P_BF    196608   /* [768] bq|bk|bv */
#define P_WOF   197376   /* [64][256] Wo */
#define P_WOBF  213760   /* [64] Wo bias */
#define P_BBF   213824   /* [4] rb bias b */
#define P_PROJ  213828   /* [30][64] proj */
#define P_TAU   215748   /* scalar */
#define P_TOTAL 215749

typedef unsigned short u16;
typedef unsigned int   u32;

__device__ __forceinline__ float u2f(u16 u) { return __uint_as_float(((u32)u) << 16); }
__device__ __forceinline__ u16  f2bf(float f) {  // round-to-nearest-even bf16
    u32 x = __float_as_uint(f);
    return (u16)((x + 0x7FFFu + ((x >> 16) & 1u)) >> 16);
}
// order-preserving float->uint encoding for atomicMax over signed floats
__device__ __forceinline__ u32  encf(float f) { u32 u = __float_as_uint(f); return (u & 0x80000000u) ? ~u : (u | 0x80000000u); }
__device__ __forceinline__ float decf(u32 u)  { return (u & 0x80000000u) ? __uint_as_float(u & 0x7FFFFFFFu) : __uint_as_float(~u); }

// ---------------- dtype detection (fp32 vs bf16 input tensors) ----------------
__global__ void k_detect(const u16* __restrict__ z, int* __restrict__ flag) {
    if (threadIdx.x == 0 && blockIdx.x == 0) {
        int bad = 0;
        for (int i = 0; i < 256; i += 2) {
            u16 u = z[i];
            int e = (u >> 7) & 0xFF;
            if (u != 0 && !(e >= 100 && e <= 140)) bad++;
        }
        *flag = (bad > 16) ? 1 : 0;   // 1 = inputs are fp32
    }
}

// ---------------- stage all small params to fp32 ----------------
__global__ __launch_bounds__(256) void k_cvt_params(
    const void* Wq, const void* Wk, const void* Wv,
    const void* bq, const void* bk, const void* bv,
    const void* Wo, const void* Wob, const void* bb, const void* proj,
    const void* taup, float* __restrict__ params, const int* __restrict__ flag)
{
    int i = blockIdx.x * 256 + threadIdx.x;
    if (i >= P_TOTAL) return;
    int f = *flag;
    if (i == P_TAU) {
        float v = f ? ((const float*)taup)[0] : u2f(((const u16*)taup)[0]);
        if (!(v > 1e-6f && v < 1e6f)) {
            float ff = ((const float*)taup)[0];
            v = (ff > 1e-6f && ff < 1e6f) ? ff : 0.25f;
        }
        params[i] = v;
        return;
    }
    const void* src; int j;
    if      (i < 65536)  { src = Wq;  j = i; }
    else if (i < 131072) { src = Wk;  j = i - 65536; }
    else if (i < 196608) { src = Wv;  j = i - 131072; }
    else if (i < 196864) { src = bq;  j = i - 196608; }
    else if (i < 197120) { src = bk;  j = i - 196864; }
    else if (i < 197376) { src = bv;  j = i - 197120; }
    else if (i < 213760) { src = Wo;  j = i - 197376; }
    else if (i < 213824) { src = Wob; j = i - 213760; }
    else if (i < 213828) { src = bb;  j = i - 213824; }
    else                 { src = proj; j = i - P_PROJ; }
    params[i] = f ? ((const float*)src)[j] : u2f(((const u16*)src)[j]);
}

// ---------------- degrees ----------------
__global__ __launch_bounds__(256) void k_deg(const int* __restrict__ ei, int* __restrict__ din, int* __restrict__ dout) {
    int e = blockIdx.x * 256 + threadIdx.x;
    if (e >= NE) return;
    atomicAdd(&dout[ei[e]], 1);
    atomicAdd(&din[ei[NE + e]], 1);
}

// ---------------- scan-free CSR offsets ----------------
__global__ __launch_bounds__(256) void k_off(const int* __restrict__ din, int* __restrict__ offn, int* __restrict__ counter) {
    __shared__ int s[256];
    __shared__ int base;
    int tid = threadIdx.x;
    int n = blockIdx.x * 256 + tid;
    int v = (n < NN) ? din[n] : 0;
    s[tid] = v;
    __syncthreads();
    for (int o = 1; o < 256; o <<= 1) {
        int t = (tid >= o) ? s[tid - o] : 0;
        __syncthreads();
        s[tid] += t;
        __syncthreads();
    }
    if (tid == 255) base = atomicAdd(counter, s[255]);
    __syncthreads();
    if (n < NN) offn[n] = base + s[tid] - v;
}

// fill CSR + precompute per-edge conv weight w = rsqrt(din[t]*dout[s])
__global__ __launch_bounds__(256) void k_fill(const int* __restrict__ ei, const int* __restrict__ offn,
                                              int* __restrict__ fill, int* __restrict__ csr,
                                              const int* __restrict__ din, const int* __restrict__ dout,
                                              float* __restrict__ wedge) {
    int e = blockIdx.x * 256 + threadIdx.x;
    if (e >= NE) return;
    int s = ei[e], t = ei[NE + e];
    int pos = offn[t] + atomicAdd(&fill[t], 1);
    csr[pos] = s;
    wedge[pos] = rsqrtf((float)din[t] * (float)dout[s]);
}

// ---------------- fused QKV GEMM + Performer feature epilogue ----------------
// grid (ceil(NN/64), 12): y 0..3 -> Q head y; y 4..7 -> K head y-4; y 8..11 -> V cols
__global__ __launch_bounds__(256) void k_gemm_feat(
    const void* __restrict__ zv, const float* __restrict__ params, const int* __restrict__ flag,
    u16* __restrict__ V16, float* __restrict__ qp, u16* __restrict__ qp16,
    float* __restrict__ dashK, float* __restrict__ diagK, u32* __restrict__ stab)
{
    __shared__ float smem[4352 + 1950];   // As(32x68)|Bs(32x68) -> tile(64x68); projL(30x65)
    __shared__ u32 smaxL;
    float* As    = smem;            // stride 68
    float* Bs    = smem + 2176;     // stride 68
    float* tile  = smem;            // 64 x 68, reuses As+Bs exactly
    float* projL = smem + 4352;     // stride 65

    const float* Wf = params + P_WF;
    const float* bf = params + P_BF;
    const int f32 = *flag;
    const int tid = threadIdx.x;
    const int bm = blockIdx.x * 64;
    const int bn = blockIdx.y * 64;

    if (bn < 512) {   // Q or K block: stage proj (padded stride 65)
        for (int i = tid; i < MF * DH; i += 256) projL[(i >> 6) * 65 + (i & 63)] = params[P_PROJ + i];
    }
    if (tid == 0) smaxL = 0u;

    const int lm = tid >> 2;          // 0..63
    const int lk = (tid & 3) * 8;     // 0,8,16,24
    const int tm = (tid >> 4) * 4;
    const int tn = (tid & 15) * 4;
    float acc[4][4] = {};

    for (int k0 = 0; k0 < 256; k0 += 32) {
        __syncthreads();
        int row = bm + lm;
        float e[8] = {0.f, 0.f, 0.f, 0.f, 0.f, 0.f, 0.f, 0.f};
        if (row < NN) {
            if (f32) {
                const float4* zp = (const float4*)((const float*)zv + (size_t)row * 256 + k0 + lk);
                float4 a = zp[0], c = zp[1];
                e[0] = a.x; e[1] = a.y; e[2] = a.z; e[3] = a.w;
                e[4] = c.x; e[5] = c.y; e[6] = c.z; e[7] = c.w;
            } else {
                uint4 av = *(const uint4*)((const u16*)zv + (size_t)row * 256 + k0 + lk);
                e[0] = __uint_as_float(av.x << 16); e[1] = __uint_as_float(av.x & 0xFFFF0000u);
                e[2] = __uint_as_float(av.y << 16); e[3] = __uint_as_float(av.y & 0xFFFF0000u);
                e[4] = __uint_as_float(av.z << 16); e[5] = __uint_as_float(av.z & 0xFFFF0000u);
                e[6] = __uint_as_float(av.w << 16); e[7] = __uint_as_float(av.w & 0xFFFF0000u);
            }
        }
        #pragma unroll
        for (int j = 0; j < 8; ++j) As[(lk + j) * 68 + lm] = e[j];
        const float4* wr = (const float4*)(Wf + (size_t)(bn + lm) * 256 + k0 + lk);
        float4 b0 = wr[0], b1 = wr[1];
        Bs[(lk + 0) * 68 + lm] = b0.x; Bs[(lk + 1) * 68 + lm] = b0.y;
        Bs[(lk + 2) * 68 + lm] = b0.z; Bs[(lk + 3) * 68 + lm] = b0.w;
        Bs[(lk + 4) * 68 + lm] = b1.x; Bs[(lk + 5) * 68 + lm] = b1.y;
        Bs[(lk + 6) * 68 + lm] = b1.z; Bs[(lk + 7) * 68 + lm] = b1.w;
        __syncthreads();
        #pragma unroll
        for (int kk = 0; kk < 32; ++kk) {
            float4 a4 = *(const float4*)(As + kk * 68 + tm);
            float4 b4 = *(const float4*)(Bs + kk * 68 + tn);
            acc[0][0] += a4.x * b4.x; acc[0][1] += a4.x * b4.y; acc[0][2] += a4.x * b4.z; acc[0][3] += a4.x * b4.w;
            acc[1][0] += a4.y * b4.x; acc[1][1] += a4.y * b4.y; acc[1][2] += a4.y * b4.z; acc[1][3] += a4.y * b4.w;
            acc[2][0] += a4.z * b4.x; acc[2][1] += a4.z * b4.y; acc[2][2] += a4.z * b4.z; acc[2][3] += a4.z * b4.w;
            acc[3][0] += a4.w * b4.x; acc[3][1] += a4.w * b4.y; acc[3][2] += a4.w * b4.z; acc[3][3] += a4.w * b4.w;
        }
    }
    __syncthreads();   // all As/Bs reads done; smem reusable as tile

    if (bn >= 512) {   // ---- V: bf16 store ----
        #pragma unroll
        for (int i = 0; i < 4; ++i) {
            int row = bm + tm + i;
            if (row < NN) {
                #pragma unroll
                for (int j = 0; j < 4; ++j)
                    V16[(size_t)row * 256 + (bn - 512) + tn + j] = f2bf(acc[i][j] + bf[bn + tn + j]);
            }
        }
        return;
    }

    // ---- Q/K: performer features on the 64x64 head tile ----
    float scale = DNRM * rsqrtf(params[P_TAU]);
    #pragma unroll
    for (int i = 0; i < 4; ++i)
        #pragma unroll
        for (int j = 0; j < 4; ++j)
            tile[(tm + i) * 68 + tn + j] = (acc[i][j] + bf[bn + tn + j]) * scale;
    __syncthreads();

    int r = tid >> 2, q = tid & 3;      // 4 lanes cooperate per row; same wave
    int n = bm + r;
    const float* trow = tile + r * 68;
    float dp = 0.f;
    #pragma unroll
    for (int d = q * 16; d < q * 16 + 16; ++d) dp += trow[d] * trow[d];
    dp += __shfl_xor(dp, 1);
    dp += __shfl_xor(dp, 2);
    float diag = dp * 0.5f;

    float dm[8];
    int nm = 0;
    float lmax = -3.0e38f;
    for (int m = q; m < MF; m += 4) {
        float s = 0.f;
        #pragma unroll
        for (int d = 0; d < DH; ++d) s += trow[d] * projL[m * 65 + d];
        dm[nm++] = s;
        lmax = fmaxf(lmax, s);
    }
    float mx = fmaxf(lmax, __shfl_xor(lmax, 1));
    mx = fmaxf(mx, __shfl_xor(mx, 2));

    if (bn < 256) {   // Q: row-local stab, write qp (fp32) + packed bf16 copy
        int h = blockIdx.y;
        if (n < NN) {
            float* o = qp + ((size_t)n * NH + h) * MF;
            u16* o16 = qp16 + ((size_t)n * NH + h) * 32;
            nm = 0;
            for (int m = q; m < MF; m += 4) {
                float v = RATIO * (expf(dm[nm++] - diag - mx) + 1e-6f);
                o[m] = v;
                o16[m] = f2bf(v);
            }
            if (q == 0) { o16[30] = 0; o16[31] = 0; }
        }
    } else {          // K: store dash/diag, global per-head max
        int h = blockIdx.y - 4;
        if (n < NN) {
            float* o = dashK + ((size_t)n * NH + h) * MF;
            nm = 0;
            for (int m = q; m < MF; m += 4) o[m] = dm[nm++];
            if (q == 0) {
                diagK[(size_t)n * NH + h] = diag;
                atomicMax(&smaxL, encf(mx));
            }
        }
        __syncthreads();
        if (tid == 0) atomicMax(&stab[h], smaxL);
    }
}

// ---------------- keys pass 2: kp in-place + kpsum + packed bf16 copy ----------------
__global__ __launch_bounds__(256) void k_kp(float* __restrict__ kp, const float* __restrict__ diagK,
                                            const u32* __restrict__ stab, float* __restrict__ kpsum,
                                            u16* __restrict__ kp16)
{
    __shared__ float part[NH * MF];
    __shared__ float stabf[4];
    int tid = threadIdx.x;
    if (tid < NH * MF) part[tid] = 0.f;
    if (tid >= 128 && tid < 132) stabf[tid - 128] = decf(stab[tid - 128]);
    __syncthreads();
    int base = blockIdx.x * 64 * MF;   // 64 rows/block, exact: 1875*64 = 120000
    for (int i = tid; i < 64 * MF; i += 256) {
        int row = blockIdx.x * 64 + i / MF;
        int m = i - (i / MF) * MF;
        int h = row & 3;
        float v = RATIO * (expf(kp[base + i] - diagK[row] - stabf[h]) + 1e-6f);
        kp[base + i] = v;
        kp16[(size_t)row * 32 + m] = f2bf(v);
        atomicAdd(&part[h * MF + m], v);
    }
    if (tid < 64) {
        int row = blockIdx.x * 64 + tid;
        kp16[(size_t)row * 32 + 30] = 0;
        kp16[(size_t)row * 32 + 31] = 0;
    }
    __syncthreads();
    if (tid < NH * MF) atomicAdd(&kpsum[tid], part[tid]);
}

// ---------------- attn_norm[n,h] = qp[n,h,:] . kpsum[h,:] ----------------
__global__ __launch_bounds__(256) void k_an(const float* __restrict__ qp, const float* __restrict__ kpsum,
                                            float* __restrict__ an)
{
    __shared__ float kps[NH * MF];
    int tid = threadIdx.x;
    if (tid < NH * MF) kps[tid] = kpsum[tid];
    __syncthreads();
    int idx = blockIdx.x * 256 + tid;
    if (idx >= NN * NH) return;
    int h = idx & 3;
    const float* q = qp + (size_t)idx * MF;
    float s = 0.f;
    #pragma unroll
    for (int m = 0; m < MF; ++m) s += q[m] * kps[h * MF + m];
    an[idx] = s;
}

// ---------------- kvs[h,k,m,d] & ksum[h,k,m] reduction over nodes ----------------
// Round 10: grid 400 -> 960 blocks (was 1.6 blocks/CU, VALUBusy 20% -- starved).
#define KVS_CHUNKS 60
#define KVS_NPB (NN / KVS_CHUNKS)    /* 500 nodes per block */
#define KVS_TS 50                    /* nodes per LDS tile */
#define KVS_DZ 16                    /* d-slice width, grid.z = DH/KVS_DZ = 4 */
__global__ __launch_bounds__(320) void k_kvs(const float* __restrict__ kp, const void* __restrict__ gum,
                                             const u16* __restrict__ V16, const int* __restrict__ flag,
                                             float* __restrict__ kvs, float* __restrict__ ksum)
{
    __shared__ float kpL[KVS_TS][MF];
    __shared__ float egL[KVS_TS][KG];
    __shared__ float vL[KVS_TS][KVS_DZ];
    int tid = threadIdx.x;
    int h = blockIdx.y;
    int z = blockIdx.z;
    int d0 = z * KVS_DZ;
    int f32 = *flag;
    int n0 = blockIdx.x * KVS_NPB;
    int ki = tid / MF, mi = tid - ki * MF;   // valid for tid<300
    float acc[KVS_DZ] = {};
    float ksacc = 0.f;
    for (int t0 = 0; t0 < KVS_NPB; t0 += KVS_TS) {
        __syncthreads();
        for (int i = tid; i < KVS_TS * MF; i += 320) {          // kp tile (coalesced)
            int j = i / MF, m = i - j * MF;
            kpL[j][m] = kp[(size_t)(n0 + t0 + j) * (NH * MF) + h * MF + m];
        }
        for (int i = tid; i < KVS_TS * KG; i += 320) {          // exp(gumbel) tile
            int j = i / KG, k = i - j * KG;
            size_t gofs = (size_t)(n0 + t0 + j) * (NH * KG) + h * KG + k;
            float g = f32 ? ((const float*)gum)[gofs] : u2f(((const u16*)gum)[gofs]);
            egL[j][k] = expf(g);
        }
        for (int i = tid; i < KVS_TS * KVS_DZ; i += 320) {      // V d-slice tile (bf16)
            int j = i / KVS_DZ, dd = i - j * KVS_DZ;
            vL[j][dd] = u2f(V16[(size_t)(n0 + t0 + j) * 256 + h * 64 + d0 + dd]);
        }
        __syncthreads();
        if (tid < KG * MF) {
            for (int j = 0; j < KVS_TS; ++j) {
                float w = kpL[j][mi] * egL[j][ki];
                ksacc += w;
                #pragma unroll
                for (int dd = 0; dd < KVS_DZ; ++dd) acc[dd] += w * vL[j][dd];
            }
        }
    }
    if (tid < KG * MF) {
        int base = ((h * KG + ki) * MF + mi) * DH + d0;
        #pragma unroll
        for (int dd = 0; dd < KVS_DZ; ++dd) atomicAdd(&kvs[base + dd], acc[dd]);
        if (z == 0) atomicAdd(&ksum[(h * KG + ki) * MF + mi], ksacc);
    }
}

// ---------------- per-edge attention weights -> link loss partials ----------------
__global__ __launch_bounds__(256) void k_edge(const int* __restrict__ ei,
                                              const u16* __restrict__ qp16, const u16* __restrict__ kp16,
                                              const float* __restrict__ an,
                                              const int* __restrict__ din, float* __restrict__ lossp)
{
    __shared__ float ls[64];
    int tid = threadIdx.x;
    int eg = tid >> 2, h = tid & 3;
    int e = blockIdx.x * 64 + eg;           // grid = NE/64 exact
    int s = ei[e], t = ei[NE + e];
    const uint4* qv = (const uint4*)(qp16 + ((size_t)t * NH + h) * 32);
    const uint4* kv = (const uint4*)(kp16 + ((size_t)s * NH + h) * 32);
    float num = 0.f;
    #pragma unroll
    for (int c = 0; c < 4; ++c) {
        uint4 a = qv[c], b = kv[c];
        num += u2f((u16)(a.x & 0xFFFF)) * u2f((u16)(b.x & 0xFFFF))
             + u2f((u16)(a.x >> 16))    * u2f((u16)(b.x >> 16))
             + u2f((u16)(a.y & 0xFFFF)) * u2f((u16)(b.y & 0xFFFF))
             + u2f((u16)(a.y >> 16))    * u2f((u16)(b.y >> 16))
             + u2f((u16)(a.z & 0xFFFF)) * u2f((u16)(b.z & 0xFFFF))
             + u2f((u16)(a.z >> 16))    * u2f((u16)(b.z >> 16))
             + u2f((u16)(a.w & 0xFFFF)) * u2f((u16)(b.w & 0xFFFF))
             + u2f((u16)(a.w >> 16))    * u2f((u16)(b.w >> 16));
    }
    float term = logf(num / an[(size_t)t * NH + h]);
    term += __shfl_xor(term, 1);
    term += __shfl_xor(term, 2);
    if (h == 0) ls[eg] = term / (float)din[t];
    __syncthreads();
    if (tid < 64) {
        float v = ls[tid];
        #pragma unroll
        for (int o = 32; o > 0; o >>= 1) v += __shfl_xor(v, o);
        if (tid == 0) atomicAdd(&lossp[blockIdx.x & 1023], v);
    }
}

// ---------------- attention readout: 48 nodes/block (3x16 sub-tiles) ----------------
// Round 10: triple sub-tiling per kvs stage -- kvs global re-read 562->187 MB,
// barriers per node /3, 48 FMA per 4 ds_read_b128 in the inner loop (was 16/2).
#define AT_NT 48
__global__ __launch_bounds__(256) void k_attn(
    const float* __restrict__ qp, const float* __restrict__ kvs, const float* __restrict__ ksum,
    u16* __restrict__ zatt)
{
    __shared__ float qpTf[3][NH * 484];       // per 16-node half: plane h [m][j] stride 16
    __shared__ float kvL[NH * 1924];          // plane h: [m][d] stride 64
    __shared__ float rdenL[3][16 * NH * KG];  // [half][j][h][k]
    __shared__ float ksL[NH * KG * MF];
    int tid = threadIdx.x;
    int n0 = blockIdx.x * AT_NT;              // grid = NN/48 = 625 exact

    for (int i = tid; i < AT_NT * NH * MF; i += 256) {   // qp -> transposed LDS
        int j48 = i / (NH * MF); int r = i - j48 * (NH * MF);
        int h = r / MF; int m = r - h * MF;
        qpTf[j48 >> 4][h * 484 + m * 16 + (j48 & 15)] = qp[(size_t)(n0 + j48) * (NH * MF) + r];
    }
    for (int i = tid; i < NH * KG * MF; i += 256) ksL[i] = ksum[i];
    __syncthreads();
    for (int i = tid; i < AT_NT * NH * KG; i += 256) {   // rden = 1/(qp.ksum)
        int j48 = i / (NH * KG); int r = i - j48 * (NH * KG);
        int h = r / KG;
        int half = j48 >> 4, j = j48 & 15;
        float s = 0.f;
        #pragma unroll
        for (int m = 0; m < MF; ++m) s += qpTf[half][h * 484 + m * 16 + j] * ksL[(r) * MF + m];
        rdenL[half][j * (NH * KG) + r] = 1.0f / s;
    }

    const int h  = tid >> 6;
    const int jg = (tid >> 4) & 3;
    const int dg = tid & 15;
    float acc[3][4][4] = {};
    for (int k = 0; k < KG; ++k) {
        __syncthreads();
        for (int i = tid; i < NH * MF * DH; i += 256) {  // stage kvs[:,k,:,:]
            int hh = i / (MF * DH); int r = i - hh * (MF * DH);
            kvL[hh * 1924 + r] = kvs[((size_t)(hh * KG + k) * MF) * DH + r];
        }
        __syncthreads();
        float ps[3][4][4] = {};
        const float* kb  = kvL + h * 1924 + dg * 4;
        const float* qb0 = qpTf[0] + h * 484 + jg * 4;
        const float* qb1 = qpTf[1] + h * 484 + jg * 4;
        const float* qb2 = qpTf[2] + h * 484 + jg * 4;
        #pragma unroll
        for (int m = 0; m < MF; ++m) {
            float4 b = *(const float4*)(kb + m * 64);
            float4 a0 = *(const float4*)(qb0 + m * 16);
            float4 a1 = *(const float4*)(qb1 + m * 16);
            float4 a2 = *(const float4*)(qb2 + m * 16);
            ps[0][0][0] += a0.x * b.x; ps[0][0][1] += a0.x * b.y; ps[0][0][2] += a0.x * b.z; ps[0][0][3] += a0.x * b.w;
            ps[0][1][0] += a0.y * b.x; ps[0][1][1] += a0.y * b.y; ps[0][1][2] += a0.y * b.z; ps[0][1][3] += a0.y * b.w;
            ps[0][2][0] += a0.z * b.x; ps[0][2][1] += a0.z * b.y; ps[0][2][2] += a0.z * b.z; ps[0][2][3] += a0.z * b.w;
            ps[0][3][0] += a0.w * b.x; ps[0][3][1] += a0.w * b.y; ps[0][3][2] += a0.w * b.z; ps[0][3][3] += a0.w * b.w;
            ps[1][0][0] += a1.x * b.x; ps[1][0][1] += a1.x * b.y; ps[1][0][2] += a1.x * b.z; ps[1][0][3] += a1.x * b.w;
            ps[1][1][0] += a1.y * b.x; ps[1][1][1] += a1.y * b.y; ps[1][1][2] += a1.y * b.z; ps[1][1][3] += a1.y * b.w;
            ps[1][2][0] += a1.z * b.x; ps[1][2][1] += a1.z * b.y; ps[1][2][2] += a1.z * b.z; ps[1][2][3] += a1.z * b.w;
            ps[1][3][0] += a1.w * b.x; ps[1][3][1] += a1.w * b.y; ps[1][3][2] += a1.w * b.z; ps[1][3][3] += a1.w * b.w;
            ps[2][0][0] += a2.x * b.x; ps[2][0][1] += a2.x * b.y; ps[2][0][2] += a2.x * b.z; ps[2][0][3] += a2.x * b.w;
            ps[2][1][0] += a2.y * b.x; ps[2][1][1] += a2.y * b.y; ps[2][1][2] += a2.y * b.z; ps[2][1][3] += a2.y * b.w;
            ps[2][2][0] += a2.z * b.x; ps[2][2][1] += a2.z * b.y; ps[2][2][2] += a2.z * b.z; ps[2][2][3] += a2.z * b.w;
            ps[2][3][0] += a2.w * b.x; ps[2][3][1] += a2.w * b.y; ps[2][3][2] += a2.w * b.z; ps[2][3][3] += a2.w * b.w;
        }
        #pragma unroll
        for (int hf = 0; hf < 3; ++hf)
            #pragma unroll
            for (int j4 = 0; j4 < 4; ++j4) {
                float rd = rdenL[hf][(jg * 4 + j4) * (NH * KG) + h * KG + k];
                #pragma unroll
                for (int d4 = 0; d4 < 4; ++d4) acc[hf][j4][d4] += ps[hf][j4][d4] * rd;
            }
    }
    #pragma unroll
    for (int hf = 0; hf < 3; ++hf)
        #pragma unroll
        for (int j4 = 0; j4 < 4; ++j4) {
            int n = n0 + hf * 16 + jg * 4 + j4;
            #pragma unroll
            for (int d4 = 0; d4 < 4; ++d4)
                zatt[(size_t)n * 256 + h * 64 + dg * 4 + d4] = f2bf(acc[hf][j4][d4] * (1.0f / KG));
        }
}

// ---------------- conv gather + zatt add + Wo projection ----------------
__global__ __launch_bounds__(256) void k_conv(
    const u16* __restrict__ zatt, const u16* __restrict__ V16,
    const int* __restrict__ csr, const float* __restrict__ wedge,
    const int* __restrict__ offn, const int* __restrict__ din,
    const float* __restrict__ params, float* __restrict__ out)
{
    __shared__ float sL[256];
    __shared__ int   sIdx[128];
    __shared__ float sW[128];
    __shared__ float sigb[4];
    int n = blockIdx.x, tid = threadIdx.x;
    if (tid < 4) sigb[tid] = 1.f / (1.f + expf(-params[P_BBF + tid]));
    int h = tid >> 6;
    int dn = din[n], o0 = offn[n];
    float cacc = 0.f;
    for (int t0 = 0; t0 < dn; t0 += 128) {
        int cnt = min(128, dn - t0);
        __syncthreads();
        if (tid < cnt) { sIdx[tid] = csr[o0 + t0 + tid]; sW[tid] = wedge[o0 + t0 + tid]; }
        __syncthreads();
        int j = 0;
        for (; j + 4 <= cnt; j += 4) {
            float v0 = u2f(V16[(size_t)sIdx[j + 0] * 256 + tid]);
            float v1 = u2f(V16[(size_t)sIdx[j + 1] * 256 + tid]);
            float v2 = u2f(V16[(size_t)sIdx[j + 2] * 256 + tid]);
            float v3 = u2f(V16[(size_t)sIdx[j + 3] * 256 + tid]);
            cacc += sW[j] * v0 + sW[j + 1] * v1 + sW[j + 2] * v2 + sW[j + 3] * v3;
        }
        for (; j < cnt; ++j) cacc += sW[j] * u2f(V16[(size_t)sIdx[j] * 256 + tid]);
    }
    __syncthreads();
    sL[tid] = u2f(zatt[(size_t)n * 256 + tid]) + sigb[h] * cacc;
    __syncthreads();
    if (tid < 64) {
        float o = params[P_WOBF + tid];
        const float4* wr = (const float4*)(params + P_WOF + (size_t)tid * 256);
        #pragma unroll 8
        for (int c4 = 0; c4 < 64; ++c4) {
            float4 u = wr[c4];
            const float* sp = sL + c4 * 4;
            o += u.x * sp[0] + u.y * sp[1] + u.z * sp[2] + u.w * sp[3];
        }
        out[(size_t)n * 64 + tid] = o;   // fp32 output, per reference dtype
    }
}

// ---------------- loss finalize ----------------
__global__ __launch_bounds__(256) void k_loss(const float* __restrict__ lossp, float* __restrict__ out) {
    __shared__ float s[256];
    int tid = threadIdx.x;
    float v = 0.f;
    for (int i = tid; i < 1024; i += 256) v += lossp[i];
    s[tid] = v;
    __syncthreads();
    for (int o = 128; o > 0; o >>= 1) {
        if (tid < o) s[tid] += s[tid + o];
        __syncthreads();
    }
    if (tid == 0) out[(size_t)NN * 64] = s[0] / (float)(NE * NH);   // fp32 output
}

extern "C" void kernel_launch(void* const* d_in, const int* in_sizes, int n_in,
                              void* d_out, int out_size, void* d_ws, size_t ws_size,
                              hipStream_t stream)
{
    const void* z    = d_in[0];
    const int*  ei   = (const int*)d_in[1];
    const void* taup = d_in[2];
    const void* gum  = d_in[3];
    const void* proj = d_in[4];
    const void* Wq   = d_in[5];
    const void* bq   = d_in[6];
    const void* Wk   = d_in[7];
    const void* bk   = d_in[8];
    const void* Wv   = d_in[9];
    const void* bv   = d_in[10];
    const void* Wo   = d_in[11];
    const void* Wob  = d_in[12];
    const void* bb   = d_in[13];
    float* out = (float*)d_out;

    // ---- workspace carve-up (fp32 units), total ~67 MB ----
    u16*   V16    = (u16*)d_ws;                    //  7,680,000 u16 : [N,256] bf16 V
    float* qpb    = (float*)d_ws + 3840000;        //  3,600,000 : [N,H,M]
    float* kpb    = qpb + (size_t)NN * NH * MF;    //  3,600,000 : dashK then kp in-place
    float* diagK  = kpb + (size_t)NN * NH * MF;    //    120,000
    float* anb    = diagK + (size_t)NN * NH;       //    120,000
    u16*   zatt   = (u16*)kpb;                     //  reuses kpb+diagK+anb (dead after k_edge)
    int*   csr    = (int*)(anb + (size_t)NN * NH); //    480,000
    int*   offn   = csr + NE;                      //     30,000
    float* params = (float*)(offn + NN);           //    215,749 (+pad to 215,752)
    // ---- zeroed accumulator region ----
    float* kvs    = params + 215752;               //     76,800 : [H,K,M,D]
    float* ksum   = kvs + NH * KG * MF * DH;       //      1,200 : [H,K,M]
    float* kpsum  = ksum + NH * KG * MF;           //        120 : [H,M]
    int*   din    = (int*)(kpsum + NH * MF);       //     30,000
    int*   doutd  = din + NN;                      //     30,000
    int*   fill   = doutd + NN;                    //     30,000
    int*   counter = fill + NN;                    //          4
    u32*   stab   = (u32*)(counter + 4);           //          4
    float* lossp  = (float*)(stab + 4);            //      1,024
    int*   flag   = (int*)(lossp + 1024);          //          4
    float* wedge  = (float*)(flag + 4);            //    480,000 (not zeroed; fully written)
    u16*   qp16   = (u16*)(wedge + NE);            //  3,840,000 u16 : [N,H,32] bf16 qp
    u16*   kp16   = qp16 + (size_t)NN * NH * 32;   //  3,840,000 u16 : [N,H,32] bf16 kp
    size_t zero_bytes = (size_t)((char*)(flag + 4) - (char*)kvs);

    hipMemsetAsync(kvs, 0, zero_bytes, stream);

    k_detect<<<dim3(1), dim3(64), 0, stream>>>((const u16*)z, flag);
    k_cvt_params<<<dim3((P_TOTAL + 255) / 256), dim3(256), 0, stream>>>(
        Wq, Wk, Wv, bq, bk, bv, Wo, Wob, bb, proj, taup, params, flag);

    k_deg <<<dim3((NE + 255) / 256), dim3(256), 0, stream>>>(ei, din, doutd);
    k_off <<<dim3((NN + 255) / 256), dim3(256), 0, stream>>>(din, offn, counter);
    k_fill<<<dim3((NE + 255) / 256), dim3(256), 0, stream>>>(ei, offn, fill, csr, din, doutd, wedge);
    k_gemm_feat<<<dim3((NN + 63) / 64, 12), dim3(256), 0, stream>>>(
        z, params, flag, V16, qpb, qp16, kpb, diagK, stab);
    k_kp  <<<dim3(NN * NH / 64), dim3(256), 0, stream>>>(kpb, diagK, stab, kpsum, kp16);
    k_an  <<<dim3((NN * NH + 255) / 256), dim3(256), 0, stream>>>(qpb, kpsum, anb);
    k_kvs <<<dim3(KVS_CHUNKS, NH, DH / KVS_DZ), dim3(320), 0, stream>>>(kpb, gum, V16, flag, kvs, ksum);
    k_edge<<<dim3(NE / 64), dim3(256), 0, stream>>>(ei, qp16, kp16, anb, din, lossp);
    // zatt overwrites kpb/diagK/anb from here on (stream-ordered after their last readers)
    k_attn<<<dim3(NN / AT_NT), dim3(256), 0, stream>>>(qpb, kvs, ksum, zatt);
    k_conv<<<dim3(NN), dim3(256), 0, stream>>>(zatt, V16, csr, wedge, offn, din, params, out);
    k_loss<<<dim3(1), dim3(256), 0, stream>>>(lossp, out);
}

// Round 11
// 1153.706 us; speedup vs baseline: 1.1170x; 1.1170x over previous
//
#include <hip/hip_runtime.h>
#include <hip/hip_bf16.h>

#define NN 30000
#define NE 480000
#define NH 4
#define DH 64
#define MF 30
#define KG 10
#define RATIO 0.18257418583505536f   /* 1/sqrt(30) */
#define DNRM  0.35355339059327373f   /* 64^-0.25  */

// fp32 params block layout (element offsets)
#define P_WF    0        /* [768][256] Wq|Wk|Wv rows */
#define P_BF    196608   /* [768] bq|bk|bv */
#define P_WOF   197376   /* [64][256] Wo */
#define P_WOBF  213760   /* [64] Wo bias */
#define P_BBF   213824   /* [4] rb bias b */
#define P_PROJ  213828   /* [30][64] proj */
#define P_TAU   215748   /* scalar */
#define P_TOTAL 215749

typedef unsigned short u16;
typedef unsigned int   u32;

__device__ __forceinline__ float u2f(u16 u) { return __uint_as_float(((u32)u) << 16); }
__device__ __forceinline__ u16  f2bf(float f) {  // round-to-nearest-even bf16
    u32 x = __float_as_uint(f);
    return (u16)((x + 0x7FFFu + ((x >> 16) & 1u)) >> 16);
}
// order-preserving float->uint encoding for atomicMax over signed floats
__device__ __forceinline__ u32  encf(float f) { u32 u = __float_as_uint(f); return (u & 0x80000000u) ? ~u : (u | 0x80000000u); }
__device__ __forceinline__ float decf(u32 u)  { return (u & 0x80000000u) ? __uint_as_float(u & 0x7FFFFFFFu) : __uint_as_float(~u); }

// ---------------- dtype detection (fp32 vs bf16 input tensors) ----------------
__global__ void k_detect(const u16* __restrict__ z, int* __restrict__ flag) {
    if (threadIdx.x == 0 && blockIdx.x == 0) {
        int bad = 0;
        for (int i = 0; i < 256; i += 2) {
            u16 u = z[i];
            int e = (u >> 7) & 0xFF;
            if (u != 0 && !(e >= 100 && e <= 140)) bad++;
        }
        *flag = (bad > 16) ? 1 : 0;   // 1 = inputs are fp32
    }
}

// ---------------- stage all small params to fp32 ----------------
__global__ __launch_bounds__(256) void k_cvt_params(
    const void* Wq, const void* Wk, const void* Wv,
    const void* bq, const void* bk, const void* bv,
    const void* Wo, const void* Wob, const void* bb, const void* proj,
    const void* taup, float* __restrict__ params, const int* __restrict__ flag)
{
    int i = blockIdx.x * 256 + threadIdx.x;
    if (i >= P_TOTAL) return;
    int f = *flag;
    if (i == P_TAU) {
        float v = f ? ((const float*)taup)[0] : u2f(((const u16*)taup)[0]);
        if (!(v > 1e-6f && v < 1e6f)) {
            float ff = ((const float*)taup)[0];
            v = (ff > 1e-6f && ff < 1e6f) ? ff : 0.25f;
        }
        params[i] = v;
        return;
    }
    const void* src; int j;
    if      (i < 65536)  { src = Wq;  j = i; }
    else if (i < 131072) { src = Wk;  j = i - 65536; }
    else if (i < 196608) { src = Wv;  j = i - 131072; }
    else if (i < 196864) { src = bq;  j = i - 196608; }
    else if (i < 197120) { src = bk;  j = i - 196864; }
    else if (i < 197376) { src = bv;  j = i - 197120; }
    else if (i < 213760) { src = Wo;  j = i - 197376; }
    else if (i < 213824) { src = Wob; j = i - 213760; }
    else if (i < 213828) { src = bb;  j = i - 213824; }
    else                 { src = proj; j = i - P_PROJ; }
    params[i] = f ? ((const float*)src)[j] : u2f(((const u16*)src)[j]);
}

// ---------------- degrees ----------------
__global__ __launch_bounds__(256) void k_deg(const int* __restrict__ ei, int* __restrict__ din, int* __restrict__ dout) {
    int e = blockIdx.x * 256 + threadIdx.x;
    if (e >= NE) return;
    atomicAdd(&dout[ei[e]], 1);
    atomicAdd(&din[ei[NE + e]], 1);
}

// ---------------- scan-free CSR offsets ----------------
__global__ __launch_bounds__(256) void k_off(const int* __restrict__ din, int* __restrict__ offn, int* __restrict__ counter) {
    __shared__ int s[256];
    __shared__ int base;
    int tid = threadIdx.x;
    int n = blockIdx.x * 256 + tid;
    int v = (n < NN) ? din[n] : 0;
    s[tid] = v;
    __syncthreads();
    for (int o = 1; o < 256; o <<= 1) {
        int t = (tid >= o) ? s[tid - o] : 0;
        __syncthreads();
        s[tid] += t;
        __syncthreads();
    }
    if (tid == 255) base = atomicAdd(counter, s[255]);
    __syncthreads();
    if (n < NN) offn[n] = base + s[tid] - v;
}

// fill CSR + precompute per-edge conv weight w = rsqrt(din[t]*dout[s])
__global__ __launch_bounds__(256) void k_fill(const int* __restrict__ ei, const int* __restrict__ offn,
                                              int* __restrict__ fill, int* __restrict__ csr,
                                              const int* __restrict__ din, const int* __restrict__ dout,
                                              float* __restrict__ wedge) {
    int e = blockIdx.x * 256 + threadIdx.x;
    if (e >= NE) return;
    int s = ei[e], t = ei[NE + e];
    int pos = offn[t] + atomicAdd(&fill[t], 1);
    csr[pos] = s;
    wedge[pos] = rsqrtf((float)din[t] * (float)dout[s]);
}

// ---------------- fused QKV GEMM + Performer feature epilogue ----------------
// grid (ceil(NN/64), 12): y 0..3 -> Q head y; y 4..7 -> K head y-4; y 8..11 -> V cols
__global__ __launch_bounds__(256) void k_gemm_feat(
    const void* __restrict__ zv, const float* __restrict__ params, const int* __restrict__ flag,
    u16* __restrict__ V16, float* __restrict__ qp, u16* __restrict__ qp16,
    float* __restrict__ dashK, float* __restrict__ diagK, u32* __restrict__ stab)
{
    __shared__ float smem[4352 + 1950];   // As(32x68)|Bs(32x68) -> tile(64x68); projL(30x65)
    __shared__ u32 smaxL;
    float* As    = smem;            // stride 68
    float* Bs    = smem + 2176;     // stride 68
    float* tile  = smem;            // 64 x 68, reuses As+Bs exactly
    float* projL = smem + 4352;     // stride 65

    const float* Wf = params + P_WF;
    const float* bf = params + P_BF;
    const int f32 = *flag;
    const int tid = threadIdx.x;
    const int bm = blockIdx.x * 64;
    const int bn = blockIdx.y * 64;

    if (bn < 512) {   // Q or K block: stage proj (padded stride 65)
        for (int i = tid; i < MF * DH; i += 256) projL[(i >> 6) * 65 + (i & 63)] = params[P_PROJ + i];
    }
    if (tid == 0) smaxL = 0u;

    const int lm = tid >> 2;          // 0..63
    const int lk = (tid & 3) * 8;     // 0,8,16,24
    const int tm = (tid >> 4) * 4;
    const int tn = (tid & 15) * 4;
    float acc[4][4] = {};

    for (int k0 = 0; k0 < 256; k0 += 32) {
        __syncthreads();
        int row = bm + lm;
        float e[8] = {0.f, 0.f, 0.f, 0.f, 0.f, 0.f, 0.f, 0.f};
        if (row < NN) {
            if (f32) {
                const float4* zp = (const float4*)((const float*)zv + (size_t)row * 256 + k0 + lk);
                float4 a = zp[0], c = zp[1];
                e[0] = a.x; e[1] = a.y; e[2] = a.z; e[3] = a.w;
                e[4] = c.x; e[5] = c.y; e[6] = c.z; e[7] = c.w;
            } else {
                uint4 av = *(const uint4*)((const u16*)zv + (size_t)row * 256 + k0 + lk);
                e[0] = __uint_as_float(av.x << 16); e[1] = __uint_as_float(av.x & 0xFFFF0000u);
                e[2] = __uint_as_float(av.y << 16); e[3] = __uint_as_float(av.y & 0xFFFF0000u);
                e[4] = __uint_as_float(av.z << 16); e[5] = __uint_as_float(av.z & 0xFFFF0000u);
                e[6] = __uint_as_float(av.w << 16); e[7] = __uint_as_float(av.w & 0xFFFF0000u);
            }
        }
        #pragma unroll
        for (int j = 0; j < 8; ++j) As[(lk + j) * 68 + lm] = e[j];
        const float4* wr = (const float4*)(Wf + (size_t)(bn + lm) * 256 + k0 + lk);
        float4 b0 = wr[0], b1 = wr[1];
        Bs[(lk + 0) * 68 + lm] = b0.x; Bs[(lk + 1) * 68 + lm] = b0.y;
        Bs[(lk + 2) * 68 + lm] = b0.z; Bs[(lk + 3) * 68 + lm] = b0.w;
        Bs[(lk + 4) * 68 + lm] = b1.x; Bs[(lk + 5) * 68 + lm] = b1.y;
        Bs[(lk + 6) * 68 + lm] = b1.z; Bs[(lk + 7) * 68 + lm] = b1.w;
        __syncthreads();
        #pragma unroll
        for (int kk = 0; kk < 32; ++kk) {
            float4 a4 = *(const float4*)(As + kk * 68 + tm);
            float4 b4 = *(const float4*)(Bs + kk * 68 + tn);
            acc[0][0] += a4.x * b4.x; acc[0][1] += a4.x * b4.y; acc[0][2] += a4.x * b4.z; acc[0][3] += a4.x * b4.w;
            acc[1][0] += a4.y * b4.x; acc[1][1] += a4.y * b4.y; acc[1][2] += a4.y * b4.z; acc[1][3] += a4.y * b4.w;
            acc[2][0] += a4.z * b4.x; acc[2][1] += a4.z * b4.y; acc[2][2] += a4.z * b4.z; acc[2][3] += a4.z * b4.w;
            acc[3][0] += a4.w * b4.x; acc[3][1] += a4.w * b4.y; acc[3][2] += a4.w * b4.z; acc[3][3] += a4.w * b4.w;
        }
    }
    __syncthreads();   // all As/Bs reads done; smem reusable as tile

    if (bn >= 512) {   // ---- V: bf16 store ----
        #pragma unroll
        for (int i = 0; i < 4; ++i) {
            int row = bm + tm + i;
            if (row < NN) {
                #pragma unroll
                for (int j = 0; j < 4; ++j)
                    V16[(size_t)row * 256 + (bn - 512) + tn + j] = f2bf(acc[i][j] + bf[bn + tn + j]);
            }
        }
        return;
    }

    // ---- Q/K: performer features on the 64x64 head tile ----
    float scale = DNRM * rsqrtf(params[P_TAU]);
    #pragma unroll
    for (int i = 0; i < 4; ++i)
        #pragma unroll
        for (int j = 0; j < 4; ++j)
            tile[(tm + i) * 68 + tn + j] = (acc[i][j] + bf[bn + tn + j]) * scale;
    __syncthreads();

    int r = tid >> 2, q = tid & 3;      // 4 lanes cooperate per row; same wave
    int n = bm + r;
    const float* trow = tile + r * 68;
    float dp = 0.f;
    #pragma unroll
    for (int d = q * 16; d < q * 16 + 16; ++d) dp += trow[d] * trow[d];
    dp += __shfl_xor(dp, 1);
    dp += __shfl_xor(dp, 2);
    float diag = dp * 0.5f;

    float dm[8];
    int nm = 0;
    float lmax = -3.0e38f;
    for (int m = q; m < MF; m += 4) {
        float s = 0.f;
        #pragma unroll
        for (int d = 0; d < DH; ++d) s += trow[d] * projL[m * 65 + d];
        dm[nm++] = s;
        lmax = fmaxf(lmax, s);
    }
    float mx = fmaxf(lmax, __shfl_xor(lmax, 1));
    mx = fmaxf(mx, __shfl_xor(mx, 2));

    if (bn < 256) {   // Q: row-local stab, write qp (fp32) + packed bf16 copy
        int h = blockIdx.y;
        if (n < NN) {
            float* o = qp + ((size_t)n * NH + h) * MF;
            u16* o16 = qp16 + ((size_t)n * NH + h) * 32;
            nm = 0;
            for (int m = q; m < MF; m += 4) {
                float v = RATIO * (expf(dm[nm++] - diag - mx) + 1e-6f);
                o[m] = v;
                o16[m] = f2bf(v);
            }
            if (q == 0) { o16[30] = 0; o16[31] = 0; }
        }
    } else {          // K: store dash/diag, global per-head max
        int h = blockIdx.y - 4;
        if (n < NN) {
            float* o = dashK + ((size_t)n * NH + h) * MF;
            nm = 0;
            for (int m = q; m < MF; m += 4) o[m] = dm[nm++];
            if (q == 0) {
                diagK[(size_t)n * NH + h] = diag;
                atomicMax(&smaxL, encf(mx));
            }
        }
        __syncthreads();
        if (tid == 0) atomicMax(&stab[h], smaxL);
    }
}

// ---------------- keys pass 2: kp in-place + kpsum + packed bf16 copy ----------------
__global__ __launch_bounds__(256) void k_kp(float* __restrict__ kp, const float* __restrict__ diagK,
                                            const u32* __restrict__ stab, float* __restrict__ kpsum,
                                            u16* __restrict__ kp16)
{
    __shared__ float part[NH * MF];
    __shared__ float stabf[4];
    int tid = threadIdx.x;
    if (tid < NH * MF) part[tid] = 0.f;
    if (tid >= 128 && tid < 132) stabf[tid - 128] = decf(stab[tid - 128]);
    __syncthreads();
    int base = blockIdx.x * 64 * MF;   // 64 rows/block, exact: 1875*64 = 120000
    for (int i = tid; i < 64 * MF; i += 256) {
        int row = blockIdx.x * 64 + i / MF;
        int m = i - (i / MF) * MF;
        int h = row & 3;
        float v = RATIO * (expf(kp[base + i] - diagK[row] - stabf[h]) + 1e-6f);
        kp[base + i] = v;
        kp16[(size_t)row * 32 + m] = f2bf(v);
        atomicAdd(&part[h * MF + m], v);
    }
    if (tid < 64) {
        int row = blockIdx.x * 64 + tid;
        kp16[(size_t)row * 32 + 30] = 0;
        kp16[(size_t)row * 32 + 31] = 0;
    }
    __syncthreads();
    if (tid < NH * MF) atomicAdd(&kpsum[tid], part[tid]);
}

// ---------------- attn_norm[n,h] = qp[n,h,:] . kpsum[h,:] ----------------
__global__ __launch_bounds__(256) void k_an(const float* __restrict__ qp, const float* __restrict__ kpsum,
                                            float* __restrict__ an)
{
    __shared__ float kps[NH * MF];
    int tid = threadIdx.x;
    if (tid < NH * MF) kps[tid] = kpsum[tid];
    __syncthreads();
    int idx = blockIdx.x * 256 + tid;
    if (idx >= NN * NH) return;
    int h = idx & 3;
    const float* q = qp + (size_t)idx * MF;
    float s = 0.f;
    #pragma unroll
    for (int m = 0; m < MF; ++m) s += q[m] * kps[h * MF + m];
    an[idx] = s;
}

// ---------------- kvs[h,k,m,d] & ksum[h,k,m] reduction over nodes ----------------
// Round 11: REVERTED to round-9 measured-best (CHUNKS 25). Round-10's 960-block
// version regressed 274->361 us: 2.4x more device-scope atomics onto the same
// 76,800 kvs addresses (WRITE_SIZE 60->144 MB) -- atomic serialization governs.
#define KVS_CHUNKS 25
#define KVS_NPB (NN / KVS_CHUNKS)    /* 1200 nodes per block */
#define KVS_TS 40                    /* nodes per LDS tile */
#define KVS_DZ 16                    /* d-slice width, grid.z = DH/KVS_DZ = 4 */
__global__ __launch_bounds__(320) void k_kvs(const float* __restrict__ kp, const void* __restrict__ gum,
                                             const u16* __restrict__ V16, const int* __restrict__ flag,
                                             float* __restrict__ kvs, float* __restrict__ ksum)
{
    __shared__ float kpL[KVS_TS][MF];
    __shared__ float egL[KVS_TS][KG];
    __shared__ float vL[KVS_TS][KVS_DZ];
    int tid = threadIdx.x;
    int h = blockIdx.y;
    int z = blockIdx.z;
    int d0 = z * KVS_DZ;
    int f32 = *flag;
    int n0 = blockIdx.x * KVS_NPB;
    int ki = tid / MF, mi = tid - ki * MF;   // valid for tid<300
    float acc[KVS_DZ] = {};
    float ksacc = 0.f;
    for (int t0 = 0; t0 < KVS_NPB; t0 += KVS_TS) {
        __syncthreads();
        for (int i = tid; i < KVS_TS * MF; i += 320) {          // kp tile (coalesced)
            int j = i / MF, m = i - j * MF;
            kpL[j][m] = kp[(size_t)(n0 + t0 + j) * (NH * MF) + h * MF + m];
        }
        for (int i = tid; i < KVS_TS * KG; i += 320) {          // exp(gumbel) tile
            int j = i / KG, k = i - j * KG;
            size_t gofs = (size_t)(n0 + t0 + j) * (NH * KG) + h * KG + k;
            float g = f32 ? ((const float*)gum)[gofs] : u2f(((const u16*)gum)[gofs]);
            egL[j][k] = expf(g);
        }
        for (int i = tid; i < KVS_TS * KVS_DZ; i += 320) {      // V d-slice tile (bf16)
            int j = i / KVS_DZ, dd = i - j * KVS_DZ;
            vL[j][dd] = u2f(V16[(size_t)(n0 + t0 + j) * 256 + h * 64 + d0 + dd]);
        }
        __syncthreads();
        if (tid < KG * MF) {
            for (int j = 0; j < KVS_TS; ++j) {
                float w = kpL[j][mi] * egL[j][ki];
                ksacc += w;
                #pragma unroll
                for (int dd = 0; dd < KVS_DZ; ++dd) acc[dd] += w * vL[j][dd];
            }
        }
    }
    if (tid < KG * MF) {
        int base = ((h * KG + ki) * MF + mi) * DH + d0;
        #pragma unroll
        for (int dd = 0; dd < KVS_DZ; ++dd) atomicAdd(&kvs[base + dd], acc[dd]);
        if (z == 0) atomicAdd(&ksum[(h * KG + ki) * MF + mi], ksacc);
    }
}

// ---------------- per-edge attention weights -> link loss partials ----------------
__global__ __launch_bounds__(256) void k_edge(const int* __restrict__ ei,
                                              const u16* __restrict__ qp16, const u16* __restrict__ kp16,
                                              const float* __restrict__ an,
                                              const int* __restrict__ din, float* __restrict__ lossp)
{
    __shared__ float ls[64];
    int tid = threadIdx.x;
    int eg = tid >> 2, h = tid & 3;
    int e = blockIdx.x * 64 + eg;           // grid = NE/64 exact
    int s = ei[e], t = ei[NE + e];
    const uint4* qv = (const uint4*)(qp16 + ((size_t)t * NH + h) * 32);
    const uint4* kv = (const uint4*)(kp16 + ((size_t)s * NH + h) * 32);
    float num = 0.f;
    #pragma unroll
    for (int c = 0; c < 4; ++c) {
        uint4 a = qv[c], b = kv[c];
        num += u2f((u16)(a.x & 0xFFFF)) * u2f((u16)(b.x & 0xFFFF))
             + u2f((u16)(a.x >> 16))    * u2f((u16)(b.x >> 16))
             + u2f((u16)(a.y & 0xFFFF)) * u2f((u16)(b.y & 0xFFFF))
             + u2f((u16)(a.y >> 16))    * u2f((u16)(b.y >> 16))
             + u2f((u16)(a.z & 0xFFFF)) * u2f((u16)(b.z & 0xFFFF))
             + u2f((u16)(a.z >> 16))    * u2f((u16)(b.z >> 16))
             + u2f((u16)(a.w & 0xFFFF)) * u2f((u16)(b.w & 0xFFFF))
             + u2f((u16)(a.w >> 16))    * u2f((u16)(b.w >> 16));
    }
    float term = logf(num / an[(size_t)t * NH + h]);
    term += __shfl_xor(term, 1);
    term += __shfl_xor(term, 2);
    if (h == 0) ls[eg] = term / (float)din[t];
    __syncthreads();
    if (tid < 64) {
        float v = ls[tid];
        #pragma unroll
        for (int o = 32; o > 0; o >>= 1) v += __shfl_xor(v, o);
        if (tid == 0) atomicAdd(&lossp[blockIdx.x & 1023], v);
    }
}

// ---------------- attention readout: 48 nodes/block (3x16 sub-tiles) ----------------
// Round 11: LDS diet -- kvs staged as bf16 (30.8->15.4 KB) and ksL overlaid in
// the same buffer; total ~47 KB -> 3 blocks/CU (was 66.5 KB -> 2 blocks/CU,
// occupancy 8.8%). u2f converts are free in this latency-bound kernel.
#define AT_NT 48
__global__ __launch_bounds__(256) void k_attn(
    const float* __restrict__ qp, const float* __restrict__ kvs, const float* __restrict__ ksum,
    u16* __restrict__ zatt)
{
    __shared__ float qpTf[3][NH * 484];       // per 16-node sub-tile: plane h [m][j] stride 16
    __shared__ u32   kvbuf[NH * 964];         // bf16 kvs plane (stride 1928 u16); prologue alias: ksL fp32
    __shared__ float rdenL[3][16 * NH * KG];  // [sub][j][h][k]
    u16*   kvL16 = (u16*)kvbuf;
    float* ksL   = (float*)kvbuf;             // 1200 floats <= 15.4 KB, dead before first kv stage
    int tid = threadIdx.x;
    int n0 = blockIdx.x * AT_NT;              // grid = NN/48 = 625 exact

    for (int i = tid; i < AT_NT * NH * MF; i += 256) {   // qp -> transposed LDS
        int j48 = i / (NH * MF); int r = i - j48 * (NH * MF);
        int h = r / MF; int m = r - h * MF;
        qpTf[j48 >> 4][h * 484 + m * 16 + (j48 & 15)] = qp[(size_t)(n0 + j48) * (NH * MF) + r];
    }
    for (int i = tid; i < NH * KG * MF; i += 256) ksL[i] = ksum[i];
    __syncthreads();
    for (int i = tid; i < AT_NT * NH * KG; i += 256) {   // rden = 1/(qp.ksum)
        int j48 = i / (NH * KG); int r = i - j48 * (NH * KG);
        int h = r / KG;
        int sub = j48 >> 4, j = j48 & 15;
        float s = 0.f;
        #pragma unroll
        for (int m = 0; m < MF; ++m) s += qpTf[sub][h * 484 + m * 16 + j] * ksL[r * MF + m];
        rdenL[sub][j * (NH * KG) + r] = 1.0f / s;
    }

    const int h  = tid >> 6;
    const int jg = (tid >> 4) & 3;
    const int dg = tid & 15;
    float acc[3][4][4] = {};
    for (int k = 0; k < KG; ++k) {
        __syncthreads();   // also protects ksL->kvL16 overlay on first iteration
        for (int i = tid; i < NH * MF * DH; i += 256) {  // stage kvs[:,k,:,:] as bf16
            int hh = i / (MF * DH); int r = i - hh * (MF * DH);
            kvL16[hh * 1928 + r] = f2bf(kvs[((size_t)(hh * KG + k) * MF) * DH + r]);
        }
        __syncthreads();
        float ps[3][4][4] = {};
        const u16* kb = kvL16 + h * 1928 + dg * 4;
        const float* qb0 = qpTf[0] + h * 484 + jg * 4;
        const float* qb1 = qpTf[1] + h * 484 + jg * 4;
        const float* qb2 = qpTf[2] + h * 484 + jg * 4;
        #pragma unroll
        for (int m = 0; m < MF; ++m) {
            ushort4 bu = *(const ushort4*)(kb + m * 64);
            float4 b = make_float4(u2f(bu.x), u2f(bu.y), u2f(bu.z), u2f(bu.w));
            float4 a0 = *(const float4*)(qb0 + m * 16);
            float4 a1 = *(const float4*)(qb1 + m * 16);
            float4 a2 = *(const float4*)(qb2 + m * 16);
            ps[0][0][0] += a0.x * b.x; ps[0][0][1] += a0.x * b.y; ps[0][0][2] += a0.x * b.z; ps[0][0][3] += a0.x * b.w;
            ps[0][1][0] += a0.y * b.x; ps[0][1][1] += a0.y * b.y; ps[0][1][2] += a0.y * b.z; ps[0][1][3] += a0.y * b.w;
            ps[0][2][0] += a0.z * b.x; ps[0][2][1] += a0.z * b.y; ps[0][2][2] += a0.z * b.z; ps[0][2][3] += a0.z * b.w;
            ps[0][3][0] += a0.w * b.x; ps[0][3][1] += a0.w * b.y; ps[0][3][2] += a0.w * b.z; ps[0][3][3] += a0.w * b.w;
            ps[1][0][0] += a1.x * b.x; ps[1][0][1] += a1.x * b.y; ps[1][0][2] += a1.x * b.z; ps[1][0][3] += a1.x * b.w;
            ps[1][1][0] += a1.y * b.x; ps[1][1][1] += a1.y * b.y; ps[1][1][2] += a1.y * b.z; ps[1][1][3] += a1.y * b.w;
            ps[1][2][0] += a1.z * b.x; ps[1][2][1] += a1.z * b.y; ps[1][2][2] += a1.z * b.z; ps[1][2][3] += a1.z * b.w;
            ps[1][3][0] += a1.w * b.x; ps[1][3][1] += a1.w * b.y; ps[1][3][2] += a1.w * b.z; ps[1][3][3] += a1.w * b.w;
            ps[2][0][0] += a2.x * b.x; ps[2][0][1] += a2.x * b.y; ps[2][0][2] += a2.x * b.z; ps[2][0][3] += a2.x * b.w;
            ps[2][1][0] += a2.y * b.x; ps[2][1][1] += a2.y * b.y; ps[2][1][2] += a2.y * b.z; ps[2][1][3] += a2.y * b.w;
            ps[2][2][0] += a2.z * b.x; ps[2][2][1] += a2.z * b.y; ps[2][2][2] += a2.z * b.z; ps[2][2][3] += a2.z * b.w;
            ps[2][3][0] += a2.w * b.x; ps[2][3][1] += a2.w * b.y; ps[2][3][2] += a2.w * b.z; ps[2][3][3] += a2.w * b.w;
        }
        #pragma unroll
        for (int sub = 0; sub < 3; ++sub)
            #pragma unroll
            for (int j4 = 0; j4 < 4; ++j4) {
                float rd = rdenL[sub][(jg * 4 + j4) * (NH * KG) + h * KG + k];
                #pragma unroll
                for (int d4 = 0; d4 < 4; ++d4) acc[sub][j4][d4] += ps[sub][j4][d4] * rd;
            }
    }
    #pragma unroll
    for (int sub = 0; sub < 3; ++sub)
        #pragma unroll
        for (int j4 = 0; j4 < 4; ++j4) {
            int n = n0 + sub * 16 + jg * 4 + j4;
            #pragma unroll
            for (int d4 = 0; d4 < 4; ++d4)
                zatt[(size_t)n * 256 + h * 64 + dg * 4 + d4] = f2bf(acc[sub][j4][d4] * (1.0f / KG));
        }
}

// ---------------- conv gather + zatt add + Wo projection ----------------
__global__ __launch_bounds__(256) void k_conv(
    const u16* __restrict__ zatt, const u16* __restrict__ V16,
    const int* __restrict__ csr, const float* __restrict__ wedge,
    const int* __restrict__ offn, const int* __restrict__ din,
    const float* __restrict__ params, float* __restrict__ out)
{
    __shared__ float sL[256];
    __shared__ int   sIdx[128];
    __shared__ float sW[128];
    __shared__ float sigb[4];
    int n = blockIdx.x, tid = threadIdx.x;
    if (tid < 4) sigb[tid] = 1.f / (1.f + expf(-params[P_BBF + tid]));
    int h = tid >> 6;
    int dn = din[n], o0 = offn[n];
    float cacc = 0.f;
    for (int t0 = 0; t0 < dn; t0 += 128) {
        int cnt = min(128, dn - t0);
        __syncthreads();
        if (tid < cnt) { sIdx[tid] = csr[o0 + t0 + tid]; sW[tid] = wedge[o0 + t0 + tid]; }
        __syncthreads();
        int j = 0;
        for (; j + 4 <= cnt; j += 4) {
            float v0 = u2f(V16[(size_t)sIdx[j + 0] * 256 + tid]);
            float v1 = u2f(V16[(size_t)sIdx[j + 1] * 256 + tid]);
            float v2 = u2f(V16[(size_t)sIdx[j + 2] * 256 + tid]);
            float v3 = u2f(V16[(size_t)sIdx[j + 3] * 256 + tid]);
            cacc += sW[j] * v0 + sW[j + 1] * v1 + sW[j + 2] * v2 + sW[j + 3] * v3;
        }
        for (; j < cnt; ++j) cacc += sW[j] * u2f(V16[(size_t)sIdx[j] * 256 + tid]);
    }
    __syncthreads();
    sL[tid] = u2f(zatt[(size_t)n * 256 + tid]) + sigb[h] * cacc;
    __syncthreads();
    if (tid < 64) {
        float o = params[P_WOBF + tid];
        const float4* wr = (const float4*)(params + P_WOF + (size_t)tid * 256);
        #pragma unroll 8
        for (int c4 = 0; c4 < 64; ++c4) {
            float4 u = wr[c4];
            const float* sp = sL + c4 * 4;
            o += u.x * sp[0] + u.y * sp[1] + u.z * sp[2] + u.w * sp[3];
        }
        out[(size_t)n * 64 + tid] = o;   // fp32 output, per reference dtype
    }
}

// ---------------- loss finalize ----------------
__global__ __launch_bounds__(256) void k_loss(const float* __restrict__ lossp, float* __restrict__ out) {
    __shared__ float s[256];
    int tid = threadIdx.x;
    float v = 0.f;
    for (int i = tid; i < 1024; i += 256) v += lossp[i];
    s[tid] = v;
    __syncthreads();
    for (int o = 128; o > 0; o >>= 1) {
        if (tid < o) s[tid] += s[tid + o];
        __syncthreads();
    }
    if (tid == 0) out[(size_t)NN * 64] = s[0] / (float)(NE * NH);   // fp32 output
}

extern "C" void kernel_launch(void* const* d_in, const int* in_sizes, int n_in,
                              void* d_out, int out_size, void* d_ws, size_t ws_size,
                              hipStream_t stream)
{
    const void* z    = d_in[0];
    const int*  ei   = (const int*)d_in[1];
    const void* taup = d_in[2];
    const void* gum  = d_in[3];
    const void* proj = d_in[4];
    const void* Wq   = d_in[5];
    const void* bq   = d_in[6];
    const void* Wk   = d_in[7];
    const void* bk   = d_in[8];
    const void* Wv   = d_in[9];
    const void* bv   = d_in[10];
    const void* Wo   = d_in[11];
    const void* Wob  = d_in[12];
    const void* bb   = d_in[13];
    float* out = (float*)d_out;

    // ---- workspace carve-up (fp32 units), total ~67 MB ----
    u16*   V16    = (u16*)d_ws;                    //  7,680,000 u16 : [N,256] bf16 V
    float* qpb    = (float*)d_ws + 3840000;        //  3,600,000 : [N,H,M]
    float* kpb    = qpb + (size_t)NN * NH * MF;    //  3,600,000 : dashK then kp in-place
    float* diagK  = kpb + (size_t)NN * NH * MF;    //    120,000
    float* anb    = diagK + (size_t)NN * NH;       //    120,000
    u16*   zatt   = (u16*)kpb;                     //  reuses kpb+diagK+anb (dead after k_edge)
    int*   csr    = (int*)(anb + (size_t)NN * NH); //    480,000
    int*   offn   = csr + NE;                      //     30,000
    float* params = (float*)(offn + NN);           //    215,749 (+pad to 215,752)
    // ---- zeroed accumulator region ----
    float* kvs    = params + 215752;               //     76,800 : [H,K,M,D]
    float* ksum   = kvs + NH * KG * MF * DH;       //      1,200 : [H,K,M]
    float* kpsum  = ksum + NH * KG * MF;           //        120 : [H,M]
    int*   din    = (int*)(kpsum + NH * MF);       //     30,000
    int*   doutd  = din + NN;                      //     30,000
    int*   fill   = doutd + NN;                    //     30,000
    int*   counter = fill + NN;                    //          4
    u32*   stab   = (u32*)(counter + 4);           //          4
    float* lossp  = (float*)(stab + 4);            //      1,024
    int*   flag   = (int*)(lossp + 1024);          //          4
    float* wedge  = (float*)(flag + 4);            //    480,000 (not zeroed; fully written)
    u16*   qp16   = (u16*)(wedge + NE);            //  3,840,000 u16 : [N,H,32] bf16 qp
    u16*   kp16   = qp16 + (size_t)NN * NH * 32;   //  3,840,000 u16 : [N,H,32] bf16 kp
    size_t zero_bytes = (size_t)((char*)(flag + 4) - (char*)kvs);

    hipMemsetAsync(kvs, 0, zero_bytes, stream);

    k_detect<<<dim3(1), dim3(64), 0, stream>>>((const u16*)z, flag);
    k_cvt_params<<<dim3((P_TOTAL + 255) / 256), dim3(256), 0, stream>>>(
        Wq, Wk, Wv, bq, bk, bv, Wo, Wob, bb, proj, taup, params, flag);

    k_deg <<<dim3((NE + 255) / 256), dim3(256), 0, stream>>>(ei, din, doutd);
    k_off <<<dim3((NN + 255) / 256), dim3(256), 0, stream>>>(din, offn, counter);
    k_fill<<<dim3((NE + 255) / 256), dim3(256), 0, stream>>>(ei, offn, fill, csr, din, doutd, wedge);
    k_gemm_feat<<<dim3((NN + 63) / 64, 12), dim3(256), 0, stream>>>(
        z, params, flag, V16, qpb, qp16, kpb, diagK, stab);
    k_kp  <<<dim3(NN * NH / 64), dim3(256), 0, stream>>>(kpb, diagK, stab, kpsum, kp16);
    k_an  <<<dim3((NN * NH + 255) / 256), dim3(256), 0, stream>>>(qpb, kpsum, anb);
    k_kvs <<<dim3(KVS_CHUNKS, NH, DH / KVS_DZ), dim3(320), 0, stream>>>(kpb, gum, V16, flag, kvs, ksum);
    k_edge<<<dim3(NE / 64), dim3(256), 0, stream>>>(ei, qp16, kp16, anb, din, lossp);
    // zatt overwrites kpb/diagK/anb from here on (stream-ordered after their last readers)
    k_attn<<<dim3(NN / AT_NT), dim3(256), 0, stream>>>(qpb, kvs, ksum, zatt);
    k_conv<<<dim3(NN), dim3(256), 0, stream>>>(zatt, V16, csr, wedge, offn, din, params, out);
    k_loss<<<dim3(1), dim3(256), 0, stream>>>(lossp, out);
}

// Round 12
// 1048.518 us; speedup vs baseline: 1.2290x; 1.1003x over previous
//
#include <hip/hip_runtime.h>
#include <hip/hip_bf16.h>

#define NN 30000
#define NE 480000
#define NH 4
#define DH 64
#define MF 30
#define KG 10
#define RATIO 0.18257418583505536f   /* 1/sqrt(30) */
#define DNRM  0.35355339059327373f   /* 64^-0.25  */

// fp32 params block layout (element offsets)
#define P_WF    0        /* [768][256] Wq|Wk|Wv rows */
#define P_BF    196608   /* [768] bq|bk|bv */
#define P_WOF   197376   /* [64][256] Wo */
#define P_WOBF  213760   /* [64] Wo bias */
#define P_BBF   213824   /* [4] rb bias b */
#define P_PROJ  213828   /* [30][64] proj */
#define P_TAU   215748   /* scalar */
#define P_TOTAL 215749

typedef unsigned short u16;
typedef unsigned int   u32;

__device__ __forceinline__ float u2f(u16 u) { return __uint_as_float(((u32)u) << 16); }
__device__ __forceinline__ u16  f2bf(float f) {  // round-to-nearest-even bf16
    u32 x = __float_as_uint(f);
    return (u16)((x + 0x7FFFu + ((x >> 16) & 1u)) >> 16);
}
// order-preserving float->uint encoding for atomicMax over signed floats
__device__ __forceinline__ u32  encf(float f) { u32 u = __float_as_uint(f); return (u & 0x80000000u) ? ~u : (u | 0x80000000u); }
__device__ __forceinline__ float decf(u32 u)  { return (u & 0x80000000u) ? __uint_as_float(u & 0x7FFFFFFFu) : __uint_as_float(~u); }

// ---------------- dtype detection (fp32 vs bf16 input tensors) ----------------
__global__ void k_detect(const u16* __restrict__ z, int* __restrict__ flag) {
    if (threadIdx.x == 0 && blockIdx.x == 0) {
        int bad = 0;
        for (int i = 0; i < 256; i += 2) {
            u16 u = z[i];
            int e = (u >> 7) & 0xFF;
            if (u != 0 && !(e >= 100 && e <= 140)) bad++;
        }
        *flag = (bad > 16) ? 1 : 0;   // 1 = inputs are fp32
    }
}

// ---------------- stage all small params to fp32 ----------------
__global__ __launch_bounds__(256) void k_cvt_params(
    const void* Wq, const void* Wk, const void* Wv,
    const void* bq, const void* bk, const void* bv,
    const void* Wo, const void* Wob, const void* bb, const void* proj,
    const void* taup, float* __restrict__ params, const int* __restrict__ flag)
{
    int i = blockIdx.x * 256 + threadIdx.x;
    if (i >= P_TOTAL) return;
    int f = *flag;
    if (i == P_TAU) {
        float v = f ? ((const float*)taup)[0] : u2f(((const u16*)taup)[0]);
        if (!(v > 1e-6f && v < 1e6f)) {
            float ff = ((const float*)taup)[0];
            v = (ff > 1e-6f && ff < 1e6f) ? ff : 0.25f;
        }
        params[i] = v;
        return;
    }
    const void* src; int j;
    if      (i < 65536)  { src = Wq;  j = i; }
    else if (i < 131072) { src = Wk;  j = i - 65536; }
    else if (i < 196608) { src = Wv;  j = i - 131072; }
    else if (i < 196864) { src = bq;  j = i - 196608; }
    else if (i < 197120) { src = bk;  j = i - 196864; }
    else if (i < 197376) { src = bv;  j = i - 197120; }
    else if (i < 213760) { src = Wo;  j = i - 197376; }
    else if (i < 213824) { src = Wob; j = i - 213760; }
    else if (i < 213828) { src = bb;  j = i - 213824; }
    else                 { src = proj; j = i - P_PROJ; }
    params[i] = f ? ((const float*)src)[j] : u2f(((const u16*)src)[j]);
}

// ---------------- degrees ----------------
__global__ __launch_bounds__(256) void k_deg(const int* __restrict__ ei, int* __restrict__ din, int* __restrict__ dout) {
    int e = blockIdx.x * 256 + threadIdx.x;
    if (e >= NE) return;
    atomicAdd(&dout[ei[e]], 1);
    atomicAdd(&din[ei[NE + e]], 1);
}

// ---------------- scan-free CSR offsets ----------------
__global__ __launch_bounds__(256) void k_off(const int* __restrict__ din, int* __restrict__ offn, int* __restrict__ counter) {
    __shared__ int s[256];
    __shared__ int base;
    int tid = threadIdx.x;
    int n = blockIdx.x * 256 + tid;
    int v = (n < NN) ? din[n] : 0;
    s[tid] = v;
    __syncthreads();
    for (int o = 1; o < 256; o <<= 1) {
        int t = (tid >= o) ? s[tid - o] : 0;
        __syncthreads();
        s[tid] += t;
        __syncthreads();
    }
    if (tid == 255) base = atomicAdd(counter, s[255]);
    __syncthreads();
    if (n < NN) offn[n] = base + s[tid] - v;
}

// fill CSR + precompute per-edge conv weight w = rsqrt(din[t]*dout[s])
__global__ __launch_bounds__(256) void k_fill(const int* __restrict__ ei, const int* __restrict__ offn,
                                              int* __restrict__ fill, int* __restrict__ csr,
                                              const int* __restrict__ din, const int* __restrict__ dout,
                                              float* __restrict__ wedge) {
    int e = blockIdx.x * 256 + threadIdx.x;
    if (e >= NE) return;
    int s = ei[e], t = ei[NE + e];
    int pos = offn[t] + atomicAdd(&fill[t], 1);
    csr[pos] = s;
    wedge[pos] = rsqrtf((float)din[t] * (float)dout[s]);
}

// ---------------- fused QKV GEMM + Performer feature epilogue ----------------
// grid (ceil(NN/64), 12): y 0..3 -> Q head y; y 4..7 -> K head y-4; y 8..11 -> V cols
__global__ __launch_bounds__(256) void k_gemm_feat(
    const void* __restrict__ zv, const float* __restrict__ params, const int* __restrict__ flag,
    u16* __restrict__ V16, float* __restrict__ qp, u16* __restrict__ qp16,
    float* __restrict__ dashK, float* __restrict__ diagK, u32* __restrict__ stab)
{
    __shared__ float smem[4352 + 1950];   // As(32x68)|Bs(32x68) -> tile(64x68); projL(30x65)
    __shared__ u32 smaxL;
    float* As    = smem;            // stride 68
    float* Bs    = smem + 2176;     // stride 68
    float* tile  = smem;            // 64 x 68, reuses As+Bs exactly
    float* projL = smem + 4352;     // stride 65

    const float* Wf = params + P_WF;
    const float* bf = params + P_BF;
    const int f32 = *flag;
    const int tid = threadIdx.x;
    const int bm = blockIdx.x * 64;
    const int bn = blockIdx.y * 64;

    if (bn < 512) {   // Q or K block: stage proj (padded stride 65)
        for (int i = tid; i < MF * DH; i += 256) projL[(i >> 6) * 65 + (i & 63)] = params[P_PROJ + i];
    }
    if (tid == 0) smaxL = 0u;

    const int lm = tid >> 2;          // 0..63
    const int lk = (tid & 3) * 8;     // 0,8,16,24
    const int tm = (tid >> 4) * 4;
    const int tn = (tid & 15) * 4;
    float acc[4][4] = {};

    for (int k0 = 0; k0 < 256; k0 += 32) {
        __syncthreads();
        int row = bm + lm;
        float e[8] = {0.f, 0.f, 0.f, 0.f, 0.f, 0.f, 0.f, 0.f};
        if (row < NN) {
            if (f32) {
                const float4* zp = (const float4*)((const float*)zv + (size_t)row * 256 + k0 + lk);
                float4 a = zp[0], c = zp[1];
                e[0] = a.x; e[1] = a.y; e[2] = a.z; e[3] = a.w;
                e[4] = c.x; e[5] = c.y; e[6] = c.z; e[7] = c.w;
            } else {
                uint4 av = *(const uint4*)((const u16*)zv + (size_t)row * 256 + k0 + lk);
                e[0] = __uint_as_float(av.x << 16); e[1] = __uint_as_float(av.x & 0xFFFF0000u);
                e[2] = __uint_as_float(av.y << 16); e[3] = __uint_as_float(av.y & 0xFFFF0000u);
                e[4] = __uint_as_float(av.z << 16); e[5] = __uint_as_float(av.z & 0xFFFF0000u);
                e[6] = __uint_as_float(av.w << 16); e[7] = __uint_as_float(av.w & 0xFFFF0000u);
            }
        }
        #pragma unroll
        for (int j = 0; j < 8; ++j) As[(lk + j) * 68 + lm] = e[j];
        const float4* wr = (const float4*)(Wf + (size_t)(bn + lm) * 256 + k0 + lk);
        float4 b0 = wr[0], b1 = wr[1];
        Bs[(lk + 0) * 68 + lm] = b0.x; Bs[(lk + 1) * 68 + lm] = b0.y;
        Bs[(lk + 2) * 68 + lm] = b0.z; Bs[(lk + 3) * 68 + lm] = b0.w;
        Bs[(lk + 4) * 68 + lm] = b1.x; Bs[(lk + 5) * 68 + lm] = b1.y;
        Bs[(lk + 6) * 68 + lm] = b1.z; Bs[(lk + 7) * 68 + lm] = b1.w;
        __syncthreads();
        #pragma unroll
        for (int kk = 0; kk < 32; ++kk) {
            float4 a4 = *(const float4*)(As + kk * 68 + tm);
            float4 b4 = *(const float4*)(Bs + kk * 68 + tn);
            acc[0][0] += a4.x * b4.x; acc[0][1] += a4.x * b4.y; acc[0][2] += a4.x * b4.z; acc[0][3] += a4.x * b4.w;
            acc[1][0] += a4.y * b4.x; acc[1][1] += a4.y * b4.y; acc[1][2] += a4.y * b4.z; acc[1][3] += a4.y * b4.w;
            acc[2][0] += a4.z * b4.x; acc[2][1] += a4.z * b4.y; acc[2][2] += a4.z * b4.z; acc[2][3] += a4.z * b4.w;
            acc[3][0] += a4.w * b4.x; acc[3][1] += a4.w * b4.y; acc[3][2] += a4.w * b4.z; acc[3][3] += a4.w * b4.w;
        }
    }
    __syncthreads();   // all As/Bs reads done; smem reusable as tile

    if (bn >= 512) {   // ---- V: bf16 store ----
        #pragma unroll
        for (int i = 0; i < 4; ++i) {
            int row = bm + tm + i;
            if (row < NN) {
                #pragma unroll
                for (int j = 0; j < 4; ++j)
                    V16[(size_t)row * 256 + (bn - 512) + tn + j] = f2bf(acc[i][j] + bf[bn + tn + j]);
            }
        }
        return;
    }

    // ---- Q/K: performer features on the 64x64 head tile ----
    float scale = DNRM * rsqrtf(params[P_TAU]);
    #pragma unroll
    for (int i = 0; i < 4; ++i)
        #pragma unroll
        for (int j = 0; j < 4; ++j)
            tile[(tm + i) * 68 + tn + j] = (acc[i][j] + bf[bn + tn + j]) * scale;
    __syncthreads();

    int r = tid >> 2, q = tid & 3;      // 4 lanes cooperate per row; same wave
    int n = bm + r;
    const float* trow = tile + r * 68;
    float dp = 0.f;
    #pragma unroll
    for (int d = q * 16; d < q * 16 + 16; ++d) dp += trow[d] * trow[d];
    dp += __shfl_xor(dp, 1);
    dp += __shfl_xor(dp, 2);
    float diag = dp * 0.5f;

    float dm[8];
    int nm = 0;
    float lmax = -3.0e38f;
    for (int m = q; m < MF; m += 4) {
        float s = 0.f;
        #pragma unroll
        for (int d = 0; d < DH; ++d) s += trow[d] * projL[m * 65 + d];
        dm[nm++] = s;
        lmax = fmaxf(lmax, s);
    }
    float mx = fmaxf(lmax, __shfl_xor(lmax, 1));
    mx = fmaxf(mx, __shfl_xor(mx, 2));

    if (bn < 256) {   // Q: row-local stab, write qp (fp32) + packed bf16 copy
        int h = blockIdx.y;
        if (n < NN) {
            float* o = qp + ((size_t)n * NH + h) * MF;
            u16* o16 = qp16 + ((size_t)n * NH + h) * 32;
            nm = 0;
            for (int m = q; m < MF; m += 4) {
                float v = RATIO * (expf(dm[nm++] - diag - mx) + 1e-6f);
                o[m] = v;
                o16[m] = f2bf(v);
            }
            if (q == 0) { o16[30] = 0; o16[31] = 0; }
        }
    } else {          // K: store dash/diag, global per-head max
        int h = blockIdx.y - 4;
        if (n < NN) {
            float* o = dashK + ((size_t)n * NH + h) * MF;
            nm = 0;
            for (int m = q; m < MF; m += 4) o[m] = dm[nm++];
            if (q == 0) {
                diagK[(size_t)n * NH + h] = diag;
                atomicMax(&smaxL, encf(mx));
            }
        }
        __syncthreads();
        if (tid == 0) atomicMax(&stab[h], smaxL);
    }
}

// ---------------- keys pass 2: kp in-place + kpsum + packed bf16 copy ----------------
__global__ __launch_bounds__(256) void k_kp(float* __restrict__ kp, const float* __restrict__ diagK,
                                            const u32* __restrict__ stab, float* __restrict__ kpsum,
                                            u16* __restrict__ kp16)
{
    __shared__ float part[NH * MF];
    __shared__ float stabf[4];
    int tid = threadIdx.x;
    if (tid < NH * MF) part[tid] = 0.f;
    if (tid >= 128 && tid < 132) stabf[tid - 128] = decf(stab[tid - 128]);
    __syncthreads();
    int base = blockIdx.x * 64 * MF;   // 64 rows/block, exact: 1875*64 = 120000
    for (int i = tid; i < 64 * MF; i += 256) {
        int row = blockIdx.x * 64 + i / MF;
        int m = i - (i / MF) * MF;
        int h = row & 3;
        float v = RATIO * (expf(kp[base + i] - diagK[row] - stabf[h]) + 1e-6f);
        kp[base + i] = v;
        kp16[(size_t)row * 32 + m] = f2bf(v);
        atomicAdd(&part[h * MF + m], v);
    }
    if (tid < 64) {
        int row = blockIdx.x * 64 + tid;
        kp16[(size_t)row * 32 + 30] = 0;
        kp16[(size_t)row * 32 + 31] = 0;
    }
    __syncthreads();
    if (tid < NH * MF) atomicAdd(&kpsum[tid], part[tid]);
}

// ---------------- attn_norm[n,h] = qp[n,h,:] . kpsum[h,:] ----------------
__global__ __launch_bounds__(256) void k_an(const float* __restrict__ qp, const float* __restrict__ kpsum,
                                            float* __restrict__ an)
{
    __shared__ float kps[NH * MF];
    int tid = threadIdx.x;
    if (tid < NH * MF) kps[tid] = kpsum[tid];
    __syncthreads();
    int idx = blockIdx.x * 256 + tid;
    if (idx >= NN * NH) return;
    int h = idx & 3;
    const float* q = qp + (size_t)idx * MF;
    float s = 0.f;
    #pragma unroll
    for (int m = 0; m < MF; ++m) s += q[m] * kps[h * MF + m];
    an[idx] = s;
}

// ---------------- kvs partial reduction over nodes (two-stage, NO atomics) ----------------
// Round 12: rounds 9/10 bracketed k_kvs -- 400 blocks can't hide barriers
// (occ 19%, VALUBusy 20.6%), 960 blocks serialize on same-address atomics
// (WRITE 60->144 MB, regressed). Escape: per-block PRIVATE partial slices
// (plain stores, deterministic), reduced by k_reduce. 50 chunks = 800 blocks
// = 3.1 blocks/CU with zero contention. Partials (15.36 MB) overlay qp16/kp16
// which are dead after k_edge (launch order: k_edge moved BEFORE k_kvs).
#define KVS_CHUNKS 50
#define KVS_NPB (NN / KVS_CHUNKS)    /* 600 nodes per block */
#define KVS_TS 40                    /* nodes per LDS tile */
#define KVS_DZ 16                    /* d-slice width, grid.z = DH/KVS_DZ = 4 */
__global__ __launch_bounds__(320) void k_kvs(const float* __restrict__ kp, const void* __restrict__ gum,
                                             const u16* __restrict__ V16, const int* __restrict__ flag,
                                             float* __restrict__ Pkvs, float* __restrict__ Pksum)
{
    __shared__ float kpL[KVS_TS][MF];
    __shared__ float egL[KVS_TS][KG];
    __shared__ float vL[KVS_TS][KVS_DZ];
    int tid = threadIdx.x;
    int h = blockIdx.y;
    int z = blockIdx.z;
    int d0 = z * KVS_DZ;
    int f32 = *flag;
    int n0 = blockIdx.x * KVS_NPB;
    int ki = tid / MF, mi = tid - ki * MF;   // valid for tid<300
    float4 acc0 = {0, 0, 0, 0}, acc1 = {0, 0, 0, 0}, acc2 = {0, 0, 0, 0}, acc3 = {0, 0, 0, 0};
    float ksacc = 0.f;
    for (int t0 = 0; t0 < KVS_NPB; t0 += KVS_TS) {
        __syncthreads();
        for (int i = tid; i < KVS_TS * MF; i += 320) {          // kp tile (coalesced)
            int j = i / MF, m = i - j * MF;
            kpL[j][m] = kp[(size_t)(n0 + t0 + j) * (NH * MF) + h * MF + m];
        }
        for (int i = tid; i < KVS_TS * KG; i += 320) {          // exp(gumbel) tile
            int j = i / KG, k = i - j * KG;
            size_t gofs = (size_t)(n0 + t0 + j) * (NH * KG) + h * KG + k;
            float g = f32 ? ((const float*)gum)[gofs] : u2f(((const u16*)gum)[gofs]);
            egL[j][k] = expf(g);
        }
        for (int i = tid; i < KVS_TS * KVS_DZ; i += 320) {      // V d-slice tile (bf16)
            int j = i / KVS_DZ, dd = i - j * KVS_DZ;
            vL[j][dd] = u2f(V16[(size_t)(n0 + t0 + j) * 256 + h * 64 + d0 + dd]);
        }
        __syncthreads();
        if (tid < KG * MF) {
            for (int j = 0; j < KVS_TS; ++j) {
                float w = kpL[j][mi] * egL[j][ki];
                ksacc += w;
                const float4* vp = (const float4*)(&vL[j][0]);   // 4x ds_read_b128
                float4 v0 = vp[0], v1 = vp[1], v2 = vp[2], v3 = vp[3];
                acc0.x += w * v0.x; acc0.y += w * v0.y; acc0.z += w * v0.z; acc0.w += w * v0.w;
                acc1.x += w * v1.x; acc1.y += w * v1.y; acc1.z += w * v1.z; acc1.w += w * v1.w;
                acc2.x += w * v2.x; acc2.y += w * v2.y; acc2.z += w * v2.z; acc2.w += w * v2.w;
                acc3.x += w * v3.x; acc3.y += w * v3.y; acc3.z += w * v3.z; acc3.w += w * v3.w;
            }
        }
    }
    if (tid < KG * MF) {
        float4* dst = (float4*)(Pkvs + (((size_t)blockIdx.x * NH + h) * 4 + z) * 4800 + tid * 16);
        dst[0] = acc0; dst[1] = acc1; dst[2] = acc2; dst[3] = acc3;
        if (z == 0) Pksum[blockIdx.x * 1200 + h * 300 + tid] = ksacc;
    }
}

// ---------------- reduce partials -> kvs, ksum ----------------
__global__ __launch_bounds__(256) void k_reduce(const float* __restrict__ Pkvs, const float* __restrict__ Pksum,
                                                float* __restrict__ kvs, float* __restrict__ ksum)
{
    int i = blockIdx.x * 256 + threadIdx.x;
    if (i < NH * KG * MF * DH) {
        int h  = i / (KG * MF * DH);
        int km = (i / DH) % (KG * MF);
        int d  = i & (DH - 1);
        size_t ofs = ((size_t)h * 4 + (d >> 4)) * 4800 + km * 16 + (d & 15);
        float s = 0.f;
        for (int c = 0; c < KVS_CHUNKS; ++c) s += Pkvs[(size_t)c * (NH * 4 * 4800) + ofs];
        kvs[i] = s;
    } else if (i < NH * KG * MF * DH + NH * KG * MF) {
        int j = i - NH * KG * MF * DH;
        float s = 0.f;
        for (int c = 0; c < KVS_CHUNKS; ++c) s += Pksum[c * 1200 + j];
        ksum[j] = s;
    }
}

// ---------------- per-edge attention weights -> link loss partials ----------------
__global__ __launch_bounds__(256) void k_edge(const int* __restrict__ ei,
                                              const u16* __restrict__ qp16, const u16* __restrict__ kp16,
                                              const float* __restrict__ an,
                                              const int* __restrict__ din, float* __restrict__ lossp)
{
    __shared__ float ls[64];
    int tid = threadIdx.x;
    int eg = tid >> 2, h = tid & 3;
    int e = blockIdx.x * 64 + eg;           // grid = NE/64 exact
    int s = ei[e], t = ei[NE + e];
    const uint4* qv = (const uint4*)(qp16 + ((size_t)t * NH + h) * 32);
    const uint4* kv = (const uint4*)(kp16 + ((size_t)s * NH + h) * 32);
    float num = 0.f;
    #pragma unroll
    for (int c = 0; c < 4; ++c) {
        uint4 a = qv[c], b = kv[c];
        num += u2f((u16)(a.x & 0xFFFF)) * u2f((u16)(b.x & 0xFFFF))
             + u2f((u16)(a.x >> 16))    * u2f((u16)(b.x >> 16))
             + u2f((u16)(a.y & 0xFFFF)) * u2f((u16)(b.y & 0xFFFF))
             + u2f((u16)(a.y >> 16))    * u2f((u16)(b.y >> 16))
             + u2f((u16)(a.z & 0xFFFF)) * u2f((u16)(b.z & 0xFFFF))
             + u2f((u16)(a.z >> 16))    * u2f((u16)(b.z >> 16))
             + u2f((u16)(a.w & 0xFFFF)) * u2f((u16)(b.w & 0xFFFF))
             + u2f((u16)(a.w >> 16))    * u2f((u16)(b.w >> 16));
    }
    float term = logf(num / an[(size_t)t * NH + h]);
    term += __shfl_xor(term, 1);
    term += __shfl_xor(term, 2);
    if (h == 0) ls[eg] = term / (float)din[t];
    __syncthreads();
    if (tid < 64) {
        float v = ls[tid];
        #pragma unroll
        for (int o = 32; o > 0; o >>= 1) v += __shfl_xor(v, o);
        if (tid == 0) atomicAdd(&lossp[blockIdx.x & 1023], v);
    }
}

// ---------------- attention readout: 48 nodes/block (3x16 sub-tiles) ----------------
#define AT_NT 48
__global__ __launch_bounds__(256) void k_attn(
    const float* __restrict__ qp, const float* __restrict__ kvs, const float* __restrict__ ksum,
    u16* __restrict__ zatt)
{
    __shared__ float qpTf[3][NH * 484];       // per 16-node sub-tile: plane h [m][j] stride 16
    __shared__ u32   kvbuf[NH * 964];         // bf16 kvs plane (stride 1928 u16); prologue alias: ksL fp32
    __shared__ float rdenL[3][16 * NH * KG];  // [sub][j][h][k]
    u16*   kvL16 = (u16*)kvbuf;
    float* ksL   = (float*)kvbuf;             // 1200 floats, dead before first kv stage
    int tid = threadIdx.x;
    int n0 = blockIdx.x * AT_NT;              // grid = NN/48 = 625 exact

    for (int i = tid; i < AT_NT * NH * MF; i += 256) {   // qp -> transposed LDS
        int j48 = i / (NH * MF); int r = i - j48 * (NH * MF);
        int h = r / MF; int m = r - h * MF;
        qpTf[j48 >> 4][h * 484 + m * 16 + (j48 & 15)] = qp[(size_t)(n0 + j48) * (NH * MF) + r];
    }
    for (int i = tid; i < NH * KG * MF; i += 256) ksL[i] = ksum[i];
    __syncthreads();
    for (int i = tid; i < AT_NT * NH * KG; i += 256) {   // rden = 1/(qp.ksum)
        int j48 = i / (NH * KG); int r = i - j48 * (NH * KG);
        int h = r / KG;
        int sub = j48 >> 4, j = j48 & 15;
        float s = 0.f;
        #pragma unroll
        for (int m = 0; m < MF; ++m) s += qpTf[sub][h * 484 + m * 16 + j] * ksL[r * MF + m];
        rdenL[sub][j * (NH * KG) + r] = 1.0f / s;
    }

    const int h  = tid >> 6;
    const int jg = (tid >> 4) & 3;
    const int dg = tid & 15;
    float acc[3][4][4] = {};
    for (int k = 0; k < KG; ++k) {
        __syncthreads();   // also protects ksL->kvL16 overlay on first iteration
        for (int i = tid; i < NH * MF * DH; i += 256) {  // stage kvs[:,k,:,:] as bf16
            int hh = i / (MF * DH); int r = i - hh * (MF * DH);
            kvL16[hh * 1928 + r] = f2bf(kvs[((size_t)(hh * KG + k) * MF) * DH + r]);
        }
        __syncthreads();
        float ps[3][4][4] = {};
        const u16* kb = kvL16 + h * 1928 + dg * 4;
        const float* qb0 = qpTf[0] + h * 484 + jg * 4;
        const float* qb1 = qpTf[1] + h * 484 + jg * 4;
        const float* qb2 = qpTf[2] + h * 484 + jg * 4;
        #pragma unroll
        for (int m = 0; m < MF; ++m) {
            ushort4 bu = *(const ushort4*)(kb + m * 64);
            float4 b = make_float4(u2f(bu.x), u2f(bu.y), u2f(bu.z), u2f(bu.w));
            float4 a0 = *(const float4*)(qb0 + m * 16);
            float4 a1 = *(const float4*)(qb1 + m * 16);
            float4 a2 = *(const float4*)(qb2 + m * 16);
            ps[0][0][0] += a0.x * b.x; ps[0][0][1] += a0.x * b.y; ps[0][0][2] += a0.x * b.z; ps[0][0][3] += a0.x * b.w;
            ps[0][1][0] += a0.y * b.x; ps[0][1][1] += a0.y * b.y; ps[0][1][2] += a0.y * b.z; ps[0][1][3] += a0.y * b.w;
            ps[0][2][0] += a0.z * b.x; ps[0][2][1] += a0.z * b.y; ps[0][2][2] += a0.z * b.z; ps[0][2][3] += a0.z * b.w;
            ps[0][3][0] += a0.w * b.x; ps[0][3][1] += a0.w * b.y; ps[0][3][2] += a0.w * b.z; ps[0][3][3] += a0.w * b.w;
            ps[1][0][0] += a1.x * b.x; ps[1][0][1] += a1.x * b.y; ps[1][0][2] += a1.x * b.z; ps[1][0][3] += a1.x * b.w;
            ps[1][1][0] += a1.y * b.x; ps[1][1][1] += a1.y * b.y; ps[1][1][2] += a1.y * b.z; ps[1][1][3] += a1.y * b.w;
            ps[1][2][0] += a1.z * b.x; ps[1][2][1] += a1.z * b.y; ps[1][2][2] += a1.z * b.z; ps[1][2][3] += a1.z * b.w;
            ps[1][3][0] += a1.w * b.x; ps[1][3][1] += a1.w * b.y; ps[1][3][2] += a1.w * b.z; ps[1][3][3] += a1.w * b.w;
            ps[2][0][0] += a2.x * b.x; ps[2][0][1] += a2.x * b.y; ps[2][0][2] += a2.x * b.z; ps[2][0][3] += a2.x * b.w;
            ps[2][1][0] += a2.y * b.x; ps[2][1][1] += a2.y * b.y; ps[2][1][2] += a2.y * b.z; ps[2][1][3] += a2.y * b.w;
            ps[2][2][0] += a2.z * b.x; ps[2][2][1] += a2.z * b.y; ps[2][2][2] += a2.z * b.z; ps[2][2][3] += a2.z * b.w;
            ps[2][3][0] += a2.w * b.x; ps[2][3][1] += a2.w * b.y; ps[2][3][2] += a2.w * b.z; ps[2][3][3] += a2.w * b.w;
        }
        #pragma unroll
        for (int sub = 0; sub < 3; ++sub)
            #pragma unroll
            for (int j4 = 0; j4 < 4; ++j4) {
                float rd = rdenL[sub][(jg * 4 + j4) * (NH * KG) + h * KG + k];
                #pragma unroll
                for (int d4 = 0; d4 < 4; ++d4) acc[sub][j4][d4] += ps[sub][j4][d4] * rd;
            }
    }
    #pragma unroll
    for (int sub = 0; sub < 3; ++sub)
        #pragma unroll
        for (int j4 = 0; j4 < 4; ++j4) {
            int n = n0 + sub * 16 + jg * 4 + j4;
            #pragma unroll
            for (int d4 = 0; d4 < 4; ++d4)
                zatt[(size_t)n * 256 + h * 64 + dg * 4 + d4] = f2bf(acc[sub][j4][d4] * (1.0f / KG));
        }
}

// ---------------- conv gather + zatt add + Wo projection ----------------
__global__ __launch_bounds__(256) void k_conv(
    const u16* __restrict__ zatt, const u16* __restrict__ V16,
    const int* __restrict__ csr, const float* __restrict__ wedge,
    const int* __restrict__ offn, const int* __restrict__ din,
    const float* __restrict__ params, float* __restrict__ out)
{
    __shared__ float sL[256];
    __shared__ int   sIdx[128];
    __shared__ float sW[128];
    __shared__ float sigb[4];
    int n = blockIdx.x, tid = threadIdx.x;
    if (tid < 4) sigb[tid] = 1.f / (1.f + expf(-params[P_BBF + tid]));
    int h = tid >> 6;
    int dn = din[n], o0 = offn[n];
    float cacc = 0.f;
    for (int t0 = 0; t0 < dn; t0 += 128) {
        int cnt = min(128, dn - t0);
        __syncthreads();
        if (tid < cnt) { sIdx[tid] = csr[o0 + t0 + tid]; sW[tid] = wedge[o0 + t0 + tid]; }
        __syncthreads();
        int j = 0;
        for (; j + 4 <= cnt; j += 4) {
            float v0 = u2f(V16[(size_t)sIdx[j + 0] * 256 + tid]);
            float v1 = u2f(V16[(size_t)sIdx[j + 1] * 256 + tid]);
            float v2 = u2f(V16[(size_t)sIdx[j + 2] * 256 + tid]);
            float v3 = u2f(V16[(size_t)sIdx[j + 3] * 256 + tid]);
            cacc += sW[j] * v0 + sW[j + 1] * v1 + sW[j + 2] * v2 + sW[j + 3] * v3;
        }
        for (; j < cnt; ++j) cacc += sW[j] * u2f(V16[(size_t)sIdx[j] * 256 + tid]);
    }
    __syncthreads();
    sL[tid] = u2f(zatt[(size_t)n * 256 + tid]) + sigb[h] * cacc;
    __syncthreads();
    if (tid < 64) {
        float o = params[P_WOBF + tid];
        const float4* wr = (const float4*)(params + P_WOF + (size_t)tid * 256);
        #pragma unroll 8
        for (int c4 = 0; c4 < 64; ++c4) {
            float4 u = wr[c4];
            const float* sp = sL + c4 * 4;
            o += u.x * sp[0] + u.y * sp[1] + u.z * sp[2] + u.w * sp[3];
        }
        out[(size_t)n * 64 + tid] = o;   // fp32 output, per reference dtype
    }
}

// ---------------- loss finalize ----------------
__global__ __launch_bounds__(256) void k_loss(const float* __restrict__ lossp, float* __restrict__ out) {
    __shared__ float s[256];
    int tid = threadIdx.x;
    float v = 0.f;
    for (int i = tid; i < 1024; i += 256) v += lossp[i];
    s[tid] = v;
    __syncthreads();
    for (int o = 128; o > 0; o >>= 1) {
        if (tid < o) s[tid] += s[tid + o];
        __syncthreads();
    }
    if (tid == 0) out[(size_t)NN * 64] = s[0] / (float)(NE * NH);   // fp32 output
}

extern "C" void kernel_launch(void* const* d_in, const int* in_sizes, int n_in,
                              void* d_out, int out_size, void* d_ws, size_t ws_size,
                              hipStream_t stream)
{
    const void* z    = d_in[0];
    const int*  ei   = (const int*)d_in[1];
    const void* taup = d_in[2];
    const void* gum  = d_in[3];
    const void* proj = d_in[4];
    const void* Wq   = d_in[5];
    const void* bq   = d_in[6];
    const void* Wk   = d_in[7];
    const void* bk   = d_in[8];
    const void* Wv   = d_in[9];
    const void* bv   = d_in[10];
    const void* Wo   = d_in[11];
    const void* Wob  = d_in[12];
    const void* bb   = d_in[13];
    float* out = (float*)d_out;

    // ---- workspace carve-up (fp32 units), total ~67 MB ----
    u16*   V16    = (u16*)d_ws;                    //  7,680,000 u16 : [N,256] bf16 V
    float* qpb    = (float*)d_ws + 3840000;        //  3,600,000 : [N,H,M]
    float* kpb    = qpb + (size_t)NN * NH * MF;    //  3,600,000 : dashK then kp in-place
    float* diagK  = kpb + (size_t)NN * NH * MF;    //    120,000
    float* anb    = diagK + (size_t)NN * NH;       //    120,000
    u16*   zatt   = (u16*)kpb;                     //  reuses kpb+diagK+anb (dead after k_edge)
    int*   csr    = (int*)(anb + (size_t)NN * NH); //    480,000
    int*   offn   = csr + NE;                      //     30,000
    float* params = (float*)(offn + NN);           //    215,749 (+pad to 215,752)
    // ---- zeroed accumulator region ----
    float* kvs    = params + 215752;               //     76,800 : [H,K,M,D]
    float* ksum   = kvs + NH * KG * MF * DH;       //      1,200 : [H,K,M]
    float* kpsum  = ksum + NH * KG * MF;           //        120 : [H,M]
    int*   din    = (int*)(kpsum + NH * MF);       //     30,000
    int*   doutd  = din + NN;                      //     30,000
    int*   fill   = doutd + NN;                    //     30,000
    int*   counter = fill + NN;                    //          4
    u32*   stab   = (u32*)(counter + 4);           //          4
    float* lossp  = (float*)(stab + 4);            //      1,024
    int*   flag   = (int*)(lossp + 1024);          //          4
    float* wedge  = (float*)(flag + 4);            //    480,000 (not zeroed; fully written)
    u16*   qp16   = (u16*)(wedge + NE);            //  3,840,000 u16 : [N,H,32] bf16 qp
    u16*   kp16   = qp16 + (size_t)NN * NH * 32;   //  3,840,000 u16 : [N,H,32] bf16 kp
    // kvs partials overlay qp16+kp16 (15.36 MB, exact fit: 50*4*4*4800 floats);
    // alive only between k_kvs and k_reduce, after qp16/kp16's last reader (k_edge).
    float* Pkvs   = (float*)qp16;
    float* Pksum  = (float*)(kp16 + (size_t)NN * NH * 32);   //  60,000 floats (new tail)
    size_t zero_bytes = (size_t)((char*)(flag + 4) - (char*)kvs);

    hipMemsetAsync(kvs, 0, zero_bytes, stream);

    k_detect<<<dim3(1), dim3(64), 0, stream>>>((const u16*)z, flag);
    k_cvt_params<<<dim3((P_TOTAL + 255) / 256), dim3(256), 0, stream>>>(
        Wq, Wk, Wv, bq, bk, bv, Wo, Wob, bb, proj, taup, params, flag);

    k_deg <<<dim3((NE + 255) / 256), dim3(256), 0, stream>>>(ei, din, doutd);
    k_off <<<dim3((NN + 255) / 256), dim3(256), 0, stream>>>(din, offn, counter);
    k_fill<<<dim3((NE + 255) / 256), dim3(256), 0, stream>>>(ei, offn, fill, csr, din, doutd, wedge);
    k_gemm_feat<<<dim3((NN + 63) / 64, 12), dim3(256), 0, stream>>>(
        z, params, flag, V16, qpb, qp16, kpb, diagK, stab);
    k_kp  <<<dim3(NN * NH / 64), dim3(256), 0, stream>>>(kpb, diagK, stab, kpsum, kp16);
    k_an  <<<dim3((NN * NH + 255) / 256), dim3(256), 0, stream>>>(qpb, kpsum, anb);
    k_edge<<<dim3(NE / 64), dim3(256), 0, stream>>>(ei, qp16, kp16, anb, din, lossp);
    // qp16/kp16 dead from here; Pkvs overlays them (stream-ordered)
    k_kvs <<<dim3(KVS_CHUNKS, NH, DH / KVS_DZ), dim3(320), 0, stream>>>(kpb, gum, V16, flag, Pkvs, Pksum);
    k_reduce<<<dim3((NH * KG * MF * DH + NH * KG * MF + 255) / 256), dim3(256), 0, stream>>>(
        Pkvs, Pksum, kvs, ksum);
    // zatt overwrites kpb/diagK/anb from here on (stream-ordered after their last readers)
    k_attn<<<dim3(NN / AT_NT), dim3(256), 0, stream>>>(qpb, kvs, ksum, zatt);
    k_conv<<<dim3(NN), dim3(256), 0, stream>>>(zatt, V16, csr, wedge, offn, din, params, out);
    k_loss<<<dim3(1), dim3(256), 0, stream>>>(lossp, out);
}

// Round 13
// 1036.275 us; speedup vs baseline: 1.2435x; 1.0118x over previous
//
#include <hip/hip_runtime.h>
#include <hip/hip_bf16.h>

#define NN 30000
#define NE 480000
#define NH 4
#define DH 64
#define MF 30
#define KG 10
#define RATIO 0.18257418583505536f   /* 1/sqrt(30) */
#define DNRM  0.35355339059327373f   /* 64^-0.25  */

// fp32 params block layout (element offsets)
#define P_WF    0        /* [768][256] Wq|Wk|Wv rows */
#define P_BF    196608   /* [768] bq|bk|bv */
#define P_WOF   197376   /* [64][256] Wo */
#define P_WOBF  213760   /* [64] Wo bias */
#define P_BBF   213824   /* [4] rb bias b */
#define P_PROJ  213828   /* [30][64] proj */
#define P_TAU   215748   /* scalar */
#define P_TOTAL 215749

typedef unsigned short u16;
typedef unsigned int   u32;

__device__ __forceinline__ float u2f(u16 u) { return __uint_as_float(((u32)u) << 16); }
__device__ __forceinline__ u16  f2bf(float f) {  // round-to-nearest-even bf16
    u32 x = __float_as_uint(f);
    return (u16)((x + 0x7FFFu + ((x >> 16) & 1u)) >> 16);
}
// order-preserving float->uint encoding for atomicMax over signed floats
__device__ __forceinline__ u32  encf(float f) { u32 u = __float_as_uint(f); return (u & 0x80000000u) ? ~u : (u | 0x80000000u); }
__device__ __forceinline__ float decf(u32 u)  { return (u & 0x80000000u) ? __uint_as_float(u & 0x7FFFFFFFu) : __uint_as_float(~u); }

// ---------------- dtype detection (fp32 vs bf16 input tensors) ----------------
__global__ void k_detect(const u16* __restrict__ z, int* __restrict__ flag) {
    if (threadIdx.x == 0 && blockIdx.x == 0) {
        int bad = 0;
        for (int i = 0; i < 256; i += 2) {
            u16 u = z[i];
            int e = (u >> 7) & 0xFF;
            if (u != 0 && !(e >= 100 && e <= 140)) bad++;
        }
        *flag = (bad > 16) ? 1 : 0;   // 1 = inputs are fp32
    }
}

// ---------------- stage all small params to fp32 ----------------
__global__ __launch_bounds__(256) void k_cvt_params(
    const void* Wq, const void* Wk, const void* Wv,
    const void* bq, const void* bk, const void* bv,
    const void* Wo, const void* Wob, const void* bb, const void* proj,
    const void* taup, float* __restrict__ params, const int* __restrict__ flag)
{
    int i = blockIdx.x * 256 + threadIdx.x;
    if (i >= P_TOTAL) return;
    int f = *flag;
    if (i == P_TAU) {
        float v = f ? ((const float*)taup)[0] : u2f(((const u16*)taup)[0]);
        if (!(v > 1e-6f && v < 1e6f)) {
            float ff = ((const float*)taup)[0];
            v = (ff > 1e-6f && ff < 1e6f) ? ff : 0.25f;
        }
        params[i] = v;
        return;
    }
    const void* src; int j;
    if      (i < 65536)  { src = Wq;  j = i; }
    else if (i < 131072) { src = Wk;  j = i - 65536; }
    else if (i < 196608) { src = Wv;  j = i - 131072; }
    else if (i < 196864) { src = bq;  j = i - 196608; }
    else if (i < 197120) { src = bk;  j = i - 196864; }
    else if (i < 197376) { src = bv;  j = i - 197120; }
    else if (i < 213760) { src = Wo;  j = i - 197376; }
    else if (i < 213824) { src = Wob; j = i - 213760; }
    else if (i < 213828) { src = bb;  j = i - 213824; }
    else                 { src = proj; j = i - P_PROJ; }
    params[i] = f ? ((const float*)src)[j] : u2f(((const u16*)src)[j]);
}

// ---------------- degrees ----------------
__global__ __launch_bounds__(256) void k_deg(const int* __restrict__ ei, int* __restrict__ din, int* __restrict__ dout) {
    int e = blockIdx.x * 256 + threadIdx.x;
    if (e >= NE) return;
    atomicAdd(&dout[ei[e]], 1);
    atomicAdd(&din[ei[NE + e]], 1);
}

// ---------------- scan-free CSR offsets ----------------
__global__ __launch_bounds__(256) void k_off(const int* __restrict__ din, int* __restrict__ offn, int* __restrict__ counter) {
    __shared__ int s[256];
    __shared__ int base;
    int tid = threadIdx.x;
    int n = blockIdx.x * 256 + tid;
    int v = (n < NN) ? din[n] : 0;
    s[tid] = v;
    __syncthreads();
    for (int o = 1; o < 256; o <<= 1) {
        int t = (tid >= o) ? s[tid - o] : 0;
        __syncthreads();
        s[tid] += t;
        __syncthreads();
    }
    if (tid == 255) base = atomicAdd(counter, s[255]);
    __syncthreads();
    if (n < NN) offn[n] = base + s[tid] - v;
}

// fill CSR + precompute per-edge conv weight w = rsqrt(din[t]*dout[s])
__global__ __launch_bounds__(256) void k_fill(const int* __restrict__ ei, const int* __restrict__ offn,
                                              int* __restrict__ fill, int* __restrict__ csr,
                                              const int* __restrict__ din, const int* __restrict__ dout,
                                              float* __restrict__ wedge) {
    int e = blockIdx.x * 256 + threadIdx.x;
    if (e >= NE) return;
    int s = ei[e], t = ei[NE + e];
    int pos = offn[t] + atomicAdd(&fill[t], 1);
    csr[pos] = s;
    wedge[pos] = rsqrtf((float)din[t] * (float)dout[s]);
}

// ---------------- fused QKV GEMM + Performer feature epilogue ----------------
// grid (ceil(NN/64), 12): y 0..3 -> Q head y; y 4..7 -> K head y-4; y 8..11 -> V cols
__global__ __launch_bounds__(256) void k_gemm_feat(
    const void* __restrict__ zv, const float* __restrict__ params, const int* __restrict__ flag,
    u16* __restrict__ V16, float* __restrict__ qp, u16* __restrict__ qp16,
    float* __restrict__ dashK, float* __restrict__ diagK, u32* __restrict__ stab)
{
    __shared__ float smem[4352 + 1950];   // As(32x68)|Bs(32x68) -> tile(64x68); projL(30x65)
    __shared__ u32 smaxL;
    float* As    = smem;            // stride 68
    float* Bs    = smem + 2176;     // stride 68
    float* tile  = smem;            // 64 x 68, reuses As+Bs exactly
    float* projL = smem + 4352;     // stride 65

    const float* Wf = params + P_WF;
    const float* bf = params + P_BF;
    const int f32 = *flag;
    const int tid = threadIdx.x;
    const int bm = blockIdx.x * 64;
    const int bn = blockIdx.y * 64;

    if (bn < 512) {   // Q or K block: stage proj (padded stride 65)
        for (int i = tid; i < MF * DH; i += 256) projL[(i >> 6) * 65 + (i & 63)] = params[P_PROJ + i];
    }
    if (tid == 0) smaxL = 0u;

    const int lm = tid >> 2;          // 0..63
    const int lk = (tid & 3) * 8;     // 0,8,16,24
    const int tm = (tid >> 4) * 4;
    const int tn = (tid & 15) * 4;
    float acc[4][4] = {};

    for (int k0 = 0; k0 < 256; k0 += 32) {
        __syncthreads();
        int row = bm + lm;
        float e[8] = {0.f, 0.f, 0.f, 0.f, 0.f, 0.f, 0.f, 0.f};
        if (row < NN) {
            if (f32) {
                const float4* zp = (const float4*)((const float*)zv + (size_t)row * 256 + k0 + lk);
                float4 a = zp[0], c = zp[1];
                e[0] = a.x; e[1] = a.y; e[2] = a.z; e[3] = a.w;
                e[4] = c.x; e[5] = c.y; e[6] = c.z; e[7] = c.w;
            } else {
                uint4 av = *(const uint4*)((const u16*)zv + (size_t)row * 256 + k0 + lk);
                e[0] = __uint_as_float(av.x << 16); e[1] = __uint_as_float(av.x & 0xFFFF0000u);
                e[2] = __uint_as_float(av.y << 16); e[3] = __uint_as_float(av.y & 0xFFFF0000u);
                e[4] = __uint_as_float(av.z << 16); e[5] = __uint_as_float(av.z & 0xFFFF0000u);
                e[6] = __uint_as_float(av.w << 16); e[7] = __uint_as_float(av.w & 0xFFFF0000u);
            }
        }
        #pragma unroll
        for (int j = 0; j < 8; ++j) As[(lk + j) * 68 + lm] = e[j];
        const float4* wr = (const float4*)(Wf + (size_t)(bn + lm) * 256 + k0 + lk);
        float4 b0 = wr[0], b1 = wr[1];
        Bs[(lk + 0) * 68 + lm] = b0.x; Bs[(lk + 1) * 68 + lm] = b0.y;
        Bs[(lk + 2) * 68 + lm] = b0.z; Bs[(lk + 3) * 68 + lm] = b0.w;
        Bs[(lk + 4) * 68 + lm] = b1.x; Bs[(lk + 5) * 68 + lm] = b1.y;
        Bs[(lk + 6) * 68 + lm] = b1.z; Bs[(lk + 7) * 68 + lm] = b1.w;
        __syncthreads();
        #pragma unroll
        for (int kk = 0; kk < 32; ++kk) {
            float4 a4 = *(const float4*)(As + kk * 68 + tm);
            float4 b4 = *(const float4*)(Bs + kk * 68 + tn);
            acc[0][0] += a4.x * b4.x; acc[0][1] += a4.x * b4.y; acc[0][2] += a4.x * b4.z; acc[0][3] += a4.x * b4.w;
            acc[1][0] += a4.y * b4.x; acc[1][1] += a4.y * b4.y; acc[1][2] += a4.y * b4.z; acc[1][3] += a4.y * b4.w;
            acc[2][0] += a4.z * b4.x; acc[2][1] += a4.z * b4.y; acc[2][2] += a4.z * b4.z; acc[2][3] += a4.z * b4.w;
            acc[3][0] += a4.w * b4.x; acc[3][1] += a4.w * b4.y; acc[3][2] += a4.w * b4.z; acc[3][3] += a4.w * b4.w;
        }
    }
    __syncthreads();   // all As/Bs reads done; smem reusable as tile

    if (bn >= 512) {   // ---- V: bf16 store ----
        #pragma unroll
        for (int i = 0; i < 4; ++i) {
            int row = bm + tm + i;
            if (row < NN) {
                #pragma unroll
                for (int j = 0; j < 4; ++j)
                    V16[(size_t)row * 256 + (bn - 512) + tn + j] = f2bf(acc[i][j] + bf[bn + tn + j]);
            }
        }
        return;
    }

    // ---- Q/K: performer features on the 64x64 head tile ----
    float scale = DNRM * rsqrtf(params[P_TAU]);
    #pragma unroll
    for (int i = 0; i < 4; ++i)
        #pragma unroll
        for (int j = 0; j < 4; ++j)
            tile[(tm + i) * 68 + tn + j] = (acc[i][j] + bf[bn + tn + j]) * scale;
    __syncthreads();

    int r = tid >> 2, q = tid & 3;      // 4 lanes cooperate per row; same wave
    int n = bm + r;
    const float* trow = tile + r * 68;
    float dp = 0.f;
    #pragma unroll
    for (int d = q * 16; d < q * 16 + 16; ++d) dp += trow[d] * trow[d];
    dp += __shfl_xor(dp, 1);
    dp += __shfl_xor(dp, 2);
    float diag = dp * 0.5f;

    float dm[8];
    int nm = 0;
    float lmax = -3.0e38f;
    for (int m = q; m < MF; m += 4) {
        float s = 0.f;
        #pragma unroll
        for (int d = 0; d < DH; ++d) s += trow[d] * projL[m * 65 + d];
        dm[nm++] = s;
        lmax = fmaxf(lmax, s);
    }
    float mx = fmaxf(lmax, __shfl_xor(lmax, 1));
    mx = fmaxf(mx, __shfl_xor(mx, 2));

    if (bn < 256) {   // Q: row-local stab, write qp (fp32) + packed bf16 copy
        int h = blockIdx.y;
        if (n < NN) {
            float* o = qp + ((size_t)n * NH + h) * MF;
            u16* o16 = qp16 + ((size_t)n * NH + h) * 32;
            nm = 0;
            for (int m = q; m < MF; m += 4) {
                float v = RATIO * (expf(dm[nm++] - diag - mx) + 1e-6f);
                o[m] = v;
                o16[m] = f2bf(v);
            }
            if (q == 0) { o16[30] = 0; o16[31] = 0; }
        }
    } else {          // K: store dash/diag, global per-head max
        int h = blockIdx.y - 4;
        if (n < NN) {
            float* o = dashK + ((size_t)n * NH + h) * MF;
            nm = 0;
            for (int m = q; m < MF; m += 4) o[m] = dm[nm++];
            if (q == 0) {
                diagK[(size_t)n * NH + h] = diag;
                atomicMax(&smaxL, encf(mx));
            }
        }
        __syncthreads();
        if (tid == 0) atomicMax(&stab[h], smaxL);
    }
}

// ---------------- keys pass 2: kp in-place + kpsum + packed bf16 copy ----------------
__global__ __launch_bounds__(256) void k_kp(float* __restrict__ kp, const float* __restrict__ diagK,
                                            const u32* __restrict__ stab, float* __restrict__ kpsum,
                                            u16* __restrict__ kp16)
{
    __shared__ float part[NH * MF];
    __shared__ float stabf[4];
    int tid = threadIdx.x;
    if (tid < NH * MF) part[tid] = 0.f;
    if (tid >= 128 && tid < 132) stabf[tid - 128] = decf(stab[tid - 128]);
    __syncthreads();
    int base = blockIdx.x * 64 * MF;   // 64 rows/block, exact: 1875*64 = 120000
    for (int i = tid; i < 64 * MF; i += 256) {
        int row = blockIdx.x * 64 + i / MF;
        int m = i - (i / MF) * MF;
        int h = row & 3;
        float v = RATIO * (expf(kp[base + i] - diagK[row] - stabf[h]) + 1e-6f);
        kp[base + i] = v;
        kp16[(size_t)row * 32 + m] = f2bf(v);
        atomicAdd(&part[h * MF + m], v);
    }
    if (tid < 64) {
        int row = blockIdx.x * 64 + tid;
        kp16[(size_t)row * 32 + 30] = 0;
        kp16[(size_t)row * 32 + 31] = 0;
    }
    __syncthreads();
    if (tid < NH * MF) atomicAdd(&kpsum[tid], part[tid]);
}

// ---------------- attn_norm[n,h] = qp[n,h,:] . kpsum[h,:] ----------------
__global__ __launch_bounds__(256) void k_an(const float* __restrict__ qp, const float* __restrict__ kpsum,
                                            float* __restrict__ an)
{
    __shared__ float kps[NH * MF];
    int tid = threadIdx.x;
    if (tid < NH * MF) kps[tid] = kpsum[tid];
    __syncthreads();
    int idx = blockIdx.x * 256 + tid;
    if (idx >= NN * NH) return;
    int h = idx & 3;
    const float* q = qp + (size_t)idx * MF;
    float s = 0.f;
    #pragma unroll
    for (int m = 0; m < MF; ++m) s += q[m] * kps[h * MF + m];
    an[idx] = s;
}

// ---------------- kvs partial reduction over nodes (two-stage, NO atomics) ----------------
#define KVS_CHUNKS 50
#define KVS_NPB (NN / KVS_CHUNKS)    /* 600 nodes per block */
#define KVS_TS 40                    /* nodes per LDS tile */
#define KVS_DZ 16                    /* d-slice width, grid.z = DH/KVS_DZ = 4 */
__global__ __launch_bounds__(320) void k_kvs(const float* __restrict__ kp, const void* __restrict__ gum,
                                             const u16* __restrict__ V16, const int* __restrict__ flag,
                                             float* __restrict__ Pkvs, float* __restrict__ Pksum)
{
    __shared__ float kpL[KVS_TS][MF];
    __shared__ float egL[KVS_TS][KG];
    __shared__ float vL[KVS_TS][KVS_DZ];
    int tid = threadIdx.x;
    int h = blockIdx.y;
    int z = blockIdx.z;
    int d0 = z * KVS_DZ;
    int f32 = *flag;
    int n0 = blockIdx.x * KVS_NPB;
    int ki = tid / MF, mi = tid - ki * MF;   // valid for tid<300
    float4 acc0 = {0, 0, 0, 0}, acc1 = {0, 0, 0, 0}, acc2 = {0, 0, 0, 0}, acc3 = {0, 0, 0, 0};
    float ksacc = 0.f;
    for (int t0 = 0; t0 < KVS_NPB; t0 += KVS_TS) {
        __syncthreads();
        for (int i = tid; i < KVS_TS * MF; i += 320) {          // kp tile (coalesced)
            int j = i / MF, m = i - j * MF;
            kpL[j][m] = kp[(size_t)(n0 + t0 + j) * (NH * MF) + h * MF + m];
        }
        for (int i = tid; i < KVS_TS * KG; i += 320) {          // exp(gumbel) tile
            int j = i / KG, k = i - j * KG;
            size_t gofs = (size_t)(n0 + t0 + j) * (NH * KG) + h * KG + k;
            float g = f32 ? ((const float*)gum)[gofs] : u2f(((const u16*)gum)[gofs]);
            egL[j][k] = expf(g);
        }
        for (int i = tid; i < KVS_TS * KVS_DZ; i += 320) {      // V d-slice tile (bf16)
            int j = i / KVS_DZ, dd = i - j * KVS_DZ;
            vL[j][dd] = u2f(V16[(size_t)(n0 + t0 + j) * 256 + h * 64 + d0 + dd]);
        }
        __syncthreads();
        if (tid < KG * MF) {
            for (int j = 0; j < KVS_TS; ++j) {
                float w = kpL[j][mi] * egL[j][ki];
                ksacc += w;
                const float4* vp = (const float4*)(&vL[j][0]);   // 4x ds_read_b128
                float4 v0 = vp[0], v1 = vp[1], v2 = vp[2], v3 = vp[3];
                acc0.x += w * v0.x; acc0.y += w * v0.y; acc0.z += w * v0.z; acc0.w += w * v0.w;
                acc1.x += w * v1.x; acc1.y += w * v1.y; acc1.z += w * v1.z; acc1.w += w * v1.w;
                acc2.x += w * v2.x; acc2.y += w * v2.y; acc2.z += w * v2.z; acc2.w += w * v2.w;
                acc3.x += w * v3.x; acc3.y += w * v3.y; acc3.z += w * v3.z; acc3.w += w * v3.w;
            }
        }
    }
    if (tid < KG * MF) {
        float4* dst = (float4*)(Pkvs + (((size_t)blockIdx.x * NH + h) * 4 + z) * 4800 + tid * 16);
        dst[0] = acc0; dst[1] = acc1; dst[2] = acc2; dst[3] = acc3;
        if (z == 0) Pksum[blockIdx.x * 1200 + h * 300 + tid] = ksacc;
    }
}

// ---------------- reduce partials -> kvs, ksum ----------------
__global__ __launch_bounds__(256) void k_reduce(const float* __restrict__ Pkvs, const float* __restrict__ Pksum,
                                                float* __restrict__ kvs, float* __restrict__ ksum)
{
    int i = blockIdx.x * 256 + threadIdx.x;
    if (i < NH * KG * MF * DH) {
        int h  = i / (KG * MF * DH);
        int km = (i / DH) % (KG * MF);
        int d  = i & (DH - 1);
        size_t ofs = ((size_t)h * 4 + (d >> 4)) * 4800 + km * 16 + (d & 15);
        float s = 0.f;
        for (int c = 0; c < KVS_CHUNKS; ++c) s += Pkvs[(size_t)c * (NH * 4 * 4800) + ofs];
        kvs[i] = s;
    } else if (i < NH * KG * MF * DH + NH * KG * MF) {
        int j = i - NH * KG * MF * DH;
        float s = 0.f;
        for (int c = 0; c < KVS_CHUNKS; ++c) s += Pksum[c * 1200 + j];
        ksum[j] = s;
    }
}

// ---------------- per-edge attention weights -> link loss partials ----------------
__global__ __launch_bounds__(256) void k_edge(const int* __restrict__ ei,
                                              const u16* __restrict__ qp16, const u16* __restrict__ kp16,
                                              const float* __restrict__ an,
                                              const int* __restrict__ din, float* __restrict__ lossp)
{
    __shared__ float ls[64];
    int tid = threadIdx.x;
    int eg = tid >> 2, h = tid & 3;
    int e = blockIdx.x * 64 + eg;           // grid = NE/64 exact
    int s = ei[e], t = ei[NE + e];
    const uint4* qv = (const uint4*)(qp16 + ((size_t)t * NH + h) * 32);
    const uint4* kv = (const uint4*)(kp16 + ((size_t)s * NH + h) * 32);
    float num = 0.f;
    #pragma unroll
    for (int c = 0; c < 4; ++c) {
        uint4 a = qv[c], b = kv[c];
        num += u2f((u16)(a.x & 0xFFFF)) * u2f((u16)(b.x & 0xFFFF))
             + u2f((u16)(a.x >> 16))    * u2f((u16)(b.x >> 16))
             + u2f((u16)(a.y & 0xFFFF)) * u2f((u16)(b.y & 0xFFFF))
             + u2f((u16)(a.y >> 16))    * u2f((u16)(b.y >> 16))
             + u2f((u16)(a.z & 0xFFFF)) * u2f((u16)(b.z & 0xFFFF))
             + u2f((u16)(a.z >> 16))    * u2f((u16)(b.z >> 16))
             + u2f((u16)(a.w & 0xFFFF)) * u2f((u16)(b.w & 0xFFFF))
             + u2f((u16)(a.w >> 16))    * u2f((u16)(b.w >> 16));
    }
    float term = logf(num / an[(size_t)t * NH + h]);
    term += __shfl_xor(term, 1);
    term += __shfl_xor(term, 2);
    if (h == 0) ls[eg] = term / (float)din[t];
    __syncthreads();
    if (tid < 64) {
        float v = ls[tid];
        #pragma unroll
        for (int o = 32; o > 0; o >>= 1) v += __shfl_xor(v, o);
        if (tid == 0) atomicAdd(&lossp[blockIdx.x & 1023], v);
    }
}

// ---------------- attention readout: 48 nodes/block (3x16 sub-tiles) ----------------
#define AT_NT 48
__global__ __launch_bounds__(256) void k_attn(
    const float* __restrict__ qp, const float* __restrict__ kvs, const float* __restrict__ ksum,
    u16* __restrict__ zatt)
{
    __shared__ float qpTf[3][NH * 484];       // per 16-node sub-tile: plane h [m][j] stride 16
    __shared__ u32   kvbuf[NH * 964];         // bf16 kvs plane (stride 1928 u16); prologue alias: ksL fp32
    __shared__ float rdenL[3][16 * NH * KG];  // [sub][j][h][k]
    u16*   kvL16 = (u16*)kvbuf;
    float* ksL   = (float*)kvbuf;             // 1200 floats, dead before first kv stage
    int tid = threadIdx.x;
    int n0 = blockIdx.x * AT_NT;              // grid = NN/48 = 625 exact

    for (int i = tid; i < AT_NT * NH * MF; i += 256) {   // qp -> transposed LDS
        int j48 = i / (NH * MF); int r = i - j48 * (NH * MF);
        int h = r / MF; int m = r - h * MF;
        qpTf[j48 >> 4][h * 484 + m * 16 + (j48 & 15)] = qp[(size_t)(n0 + j48) * (NH * MF) + r];
    }
    for (int i = tid; i < NH * KG * MF; i += 256) ksL[i] = ksum[i];
    __syncthreads();
    for (int i = tid; i < AT_NT * NH * KG; i += 256) {   // rden = 1/(qp.ksum)
        int j48 = i / (NH * KG); int r = i - j48 * (NH * KG);
        int h = r / KG;
        int sub = j48 >> 4, j = j48 & 15;
        float s = 0.f;
        #pragma unroll
        for (int m = 0; m < MF; ++m) s += qpTf[sub][h * 484 + m * 16 + j] * ksL[r * MF + m];
        rdenL[sub][j * (NH * KG) + r] = 1.0f / s;
    }

    const int h  = tid >> 6;
    const int jg = (tid >> 4) & 3;
    const int dg = tid & 15;
    float acc[3][4][4] = {};
    for (int k = 0; k < KG; ++k) {
        __syncthreads();   // also protects ksL->kvL16 overlay on first iteration
        for (int i = tid; i < NH * MF * DH; i += 256) {  // stage kvs[:,k,:,:] as bf16
            int hh = i / (MF * DH); int r = i - hh * (MF * DH);
            kvL16[hh * 1928 + r] = f2bf(kvs[((size_t)(hh * KG + k) * MF) * DH + r]);
        }
        __syncthreads();
        float ps[3][4][4] = {};
        const u16* kb = kvL16 + h * 1928 + dg * 4;
        const float* qb0 = qpTf[0] + h * 484 + jg * 4;
        const float* qb1 = qpTf[1] + h * 484 + jg * 4;
        const float* qb2 = qpTf[2] + h * 484 + jg * 4;
        #pragma unroll
        for (int m = 0; m < MF; ++m) {
            ushort4 bu = *(const ushort4*)(kb + m * 64);
            float4 b = make_float4(u2f(bu.x), u2f(bu.y), u2f(bu.z), u2f(bu.w));
            float4 a0 = *(const float4*)(qb0 + m * 16);
            float4 a1 = *(const float4*)(qb1 + m * 16);
            float4 a2 = *(const float4*)(qb2 + m * 16);
            ps[0][0][0] += a0.x * b.x; ps[0][0][1] += a0.x * b.y; ps[0][0][2] += a0.x * b.z; ps[0][0][3] += a0.x * b.w;
            ps[0][1][0] += a0.y * b.x; ps[0][1][1] += a0.y * b.y; ps[0][1][2] += a0.y * b.z; ps[0][1][3] += a0.y * b.w;
            ps[0][2][0] += a0.z * b.x; ps[0][2][1] += a0.z * b.y; ps[0][2][2] += a0.z * b.z; ps[0][2][3] += a0.z * b.w;
            ps[0][3][0] += a0.w * b.x; ps[0][3][1] += a0.w * b.y; ps[0][3][2] += a0.w * b.z; ps[0][3][3] += a0.w * b.w;
            ps[1][0][0] += a1.x * b.x; ps[1][0][1] += a1.x * b.y; ps[1][0][2] += a1.x * b.z; ps[1][0][3] += a1.x * b.w;
            ps[1][1][0] += a1.y * b.x; ps[1][1][1] += a1.y * b.y; ps[1][1][2] += a1.y * b.z; ps[1][1][3] += a1.y * b.w;
            ps[1][2][0] += a1.z * b.x; ps[1][2][1] += a1.z * b.y; ps[1][2][2] += a1.z * b.z; ps[1][2][3] += a1.z * b.w;
            ps[1][3][0] += a1.w * b.x; ps[1][3][1] += a1.w * b.y; ps[1][3][2] += a1.w * b.z; ps[1][3][3] += a1.w * b.w;
            ps[2][0][0] += a2.x * b.x; ps[2][0][1] += a2.x * b.y; ps[2][0][2] += a2.x * b.z; ps[2][0][3] += a2.x * b.w;
            ps[2][1][0] += a2.y * b.x; ps[2][1][1] += a2.y * b.y; ps[2][1][2] += a2.y * b.z; ps[2][1][3] += a2.y * b.w;
            ps[2][2][0] += a2.z * b.x; ps[2][2][1] += a2.z * b.y; ps[2][2][2] += a2.z * b.z; ps[2][2][3] += a2.z * b.w;
            ps[2][3][0] += a2.w * b.x; ps[2][3][1] += a2.w * b.y; ps[2][3][2] += a2.w * b.z; ps[2][3][3] += a2.w * b.w;
        }
        #pragma unroll
        for (int sub = 0; sub < 3; ++sub)
            #pragma unroll
            for (int j4 = 0; j4 < 4; ++j4) {
                float rd = rdenL[sub][(jg * 4 + j4) * (NH * KG) + h * KG + k];
                #pragma unroll
                for (int d4 = 0; d4 < 4; ++d4) acc[sub][j4][d4] += ps[sub][j4][d4] * rd;
            }
    }
    #pragma unroll
    for (int sub = 0; sub < 3; ++sub)
        #pragma unroll
        for (int j4 = 0; j4 < 4; ++j4) {
            int n = n0 + sub * 16 + jg * 4 + j4;
            #pragma unroll
            for (int d4 = 0; d4 < 4; ++d4)
                zatt[(size_t)n * 256 + h * 64 + dg * 4 + d4] = f2bf(acc[sub][j4][d4] * (1.0f / KG));
        }
}

// ---------------- conv gather + zatt add + Wo projection ----------------
// Round 13: edge-parallel waves. Round-12 version issued 2 B/lane ushort
// gathers (4 wave-insts per 512 B row, 4 rows in flight -> L3-latency bound at
// VALUBusy 18%). Now each wave owns an edge; lane l loads uint2 (8 B = 4 bf16)
// -> one wave-inst per row, 4 rows/issue x 2-deep unroll = 8 rows in flight.
__global__ __launch_bounds__(256) void k_conv(
    const u16* __restrict__ zatt, const u16* __restrict__ V16,
    const int* __restrict__ csr, const float* __restrict__ wedge,
    const int* __restrict__ offn, const int* __restrict__ din,
    const float* __restrict__ params, float* __restrict__ out)
{
    __shared__ float sP[4][256];
    __shared__ float sL[256];
    __shared__ int   sIdx[64];
    __shared__ float sW[64];
    __shared__ float sigb[4];
    int n = blockIdx.x, tid = threadIdx.x;
    if (tid < 4) sigb[tid] = 1.f / (1.f + expf(-params[P_BBF + tid]));
    const int g = tid >> 6;       // wave id = edge slot
    const int l = tid & 63;       // lane: d-range 4l..4l+3
    int dn = din[n], o0 = offn[n];
    float c0 = 0.f, c1 = 0.f, c2 = 0.f, c3 = 0.f;
    for (int t0 = 0; t0 < dn; t0 += 64) {
        int cnt = min(64, dn - t0);
        __syncthreads();
        if (tid < cnt) { sIdx[tid] = csr[o0 + t0 + tid]; sW[tid] = wedge[o0 + t0 + tid]; }
        __syncthreads();
        int j = g;
        for (; j + 4 < cnt; j += 8) {   // 2-deep unroll: rows j and j+4 in flight
            uint2 va = *(const uint2*)(V16 + (size_t)sIdx[j] * 256 + l * 4);
            uint2 vb = *(const uint2*)(V16 + (size_t)sIdx[j + 4] * 256 + l * 4);
            float wa = sW[j], wb = sW[j + 4];
            c0 += wa * u2f((u16)(va.x & 0xFFFF)) + wb * u2f((u16)(vb.x & 0xFFFF));
            c1 += wa * u2f((u16)(va.x >> 16))    + wb * u2f((u16)(vb.x >> 16));
            c2 += wa * u2f((u16)(va.y & 0xFFFF)) + wb * u2f((u16)(vb.y & 0xFFFF));
            c3 += wa * u2f((u16)(va.y >> 16))    + wb * u2f((u16)(vb.y >> 16));
        }
        if (j < cnt) {
            uint2 va = *(const uint2*)(V16 + (size_t)sIdx[j] * 256 + l * 4);
            float wa = sW[j];
            c0 += wa * u2f((u16)(va.x & 0xFFFF));
            c1 += wa * u2f((u16)(va.x >> 16));
            c2 += wa * u2f((u16)(va.y & 0xFFFF));
            c3 += wa * u2f((u16)(va.y >> 16));
        }
    }
    sP[g][l * 4 + 0] = c0; sP[g][l * 4 + 1] = c1; sP[g][l * 4 + 2] = c2; sP[g][l * 4 + 3] = c3;
    __syncthreads();
    float cacc = sP[0][tid] + sP[1][tid] + sP[2][tid] + sP[3][tid];
    sL[tid] = u2f(zatt[(size_t)n * 256 + tid]) + sigb[tid >> 6] * cacc;
    __syncthreads();
    if (tid < 64) {
        float o = params[P_WOBF + tid];
        const float4* wr = (const float4*)(params + P_WOF + (size_t)tid * 256);
        #pragma unroll 8
        for (int c4 = 0; c4 < 64; ++c4) {
            float4 u = wr[c4];
            const float* sp = sL + c4 * 4;
            o += u.x * sp[0] + u.y * sp[1] + u.z * sp[2] + u.w * sp[3];
        }
        out[(size_t)n * 64 + tid] = o;   // fp32 output, per reference dtype
    }
}

// ---------------- loss finalize ----------------
__global__ __launch_bounds__(256) void k_loss(const float* __restrict__ lossp, float* __restrict__ out) {
    __shared__ float s[256];
    int tid = threadIdx.x;
    float v = 0.f;
    for (int i = tid; i < 1024; i += 256) v += lossp[i];
    s[tid] = v;
    __syncthreads();
    for (int o = 128; o > 0; o >>= 1) {
        if (tid < o) s[tid] += s[tid + o];
        __syncthreads();
    }
    if (tid == 0) out[(size_t)NN * 64] = s[0] / (float)(NE * NH);   // fp32 output
}

extern "C" void kernel_launch(void* const* d_in, const int* in_sizes, int n_in,
                              void* d_out, int out_size, void* d_ws, size_t ws_size,
                              hipStream_t stream)
{
    const void* z    = d_in[0];
    const int*  ei   = (const int*)d_in[1];
    const void* taup = d_in[2];
    const void* gum  = d_in[3];
    const void* proj = d_in[4];
    const void* Wq   = d_in[5];
    const void* bq   = d_in[6];
    const void* Wk   = d_in[7];
    const void* bk   = d_in[8];
    const void* Wv   = d_in[9];
    const void* bv   = d_in[10];
    const void* Wo   = d_in[11];
    const void* Wob  = d_in[12];
    const void* bb   = d_in[13];
    float* out = (float*)d_out;

    // ---- workspace carve-up (fp32 units), total ~67 MB ----
    u16*   V16    = (u16*)d_ws;                    //  7,680,000 u16 : [N,256] bf16 V
    float* qpb    = (float*)d_ws + 3840000;        //  3,600,000 : [N,H,M]
    float* kpb    = qpb + (size_t)NN * NH * MF;    //  3,600,000 : dashK then kp in-place
    float* diagK  = kpb + (size_t)NN * NH * MF;    //    120,000
    float* anb    = diagK + (size_t)NN * NH;       //    120,000
    u16*   zatt   = (u16*)kpb;                     //  reuses kpb+diagK+anb (dead after k_edge)
    int*   csr    = (int*)(anb + (size_t)NN * NH); //    480,000
    int*   offn   = csr + NE;                      //     30,000
    float* params = (float*)(offn + NN);           //    215,749 (+pad to 215,752)
    // ---- zeroed accumulator region ----
    float* kvs    = params + 215752;               //     76,800 : [H,K,M,D]
    float* ksum   = kvs + NH * KG * MF * DH;       //      1,200 : [H,K,M]
    float* kpsum  = ksum + NH * KG * MF;           //        120 : [H,M]
    int*   din    = (int*)(kpsum + NH * MF);       //     30,000
    int*   doutd  = din + NN;                      //     30,000
    int*   fill   = doutd + NN;                    //     30,000
    int*   counter = fill + NN;                    //          4
    u32*   stab   = (u32*)(counter + 4);           //          4
    float* lossp  = (float*)(stab + 4);            //      1,024
    int*   flag   = (int*)(lossp + 1024);          //          4
    float* wedge  = (float*)(flag + 4);            //    480,000 (not zeroed; fully written)
    u16*   qp16   = (u16*)(wedge + NE);            //  3,840,000 u16 : [N,H,32] bf16 qp
    u16*   kp16   = qp16 + (size_t)NN * NH * 32;   //  3,840,000 u16 : [N,H,32] bf16 kp
    // kvs partials overlay qp16+kp16 (15.36 MB, exact fit: 50*4*4*4800 floats);
    // alive only between k_kvs and k_reduce, after qp16/kp16's last reader (k_edge).
    float* Pkvs   = (float*)qp16;
    float* Pksum  = (float*)(kp16 + (size_t)NN * NH * 32);   //  60,000 floats (new tail)
    size_t zero_bytes = (size_t)((char*)(flag + 4) - (char*)kvs);

    hipMemsetAsync(kvs, 0, zero_bytes, stream);

    k_detect<<<dim3(1), dim3(64), 0, stream>>>((const u16*)z, flag);
    k_cvt_params<<<dim3((P_TOTAL + 255) / 256), dim3(256), 0, stream>>>(
        Wq, Wk, Wv, bq, bk, bv, Wo, Wob, bb, proj, taup, params, flag);

    k_deg <<<dim3((NE + 255) / 256), dim3(256), 0, stream>>>(ei, din, doutd);
    k_off <<<dim3((NN + 255) / 256), dim3(256), 0, stream>>>(din, offn, counter);
    k_fill<<<dim3((NE + 255) / 256), dim3(256), 0, stream>>>(ei, offn, fill, csr, din, doutd, wedge);
    k_gemm_feat<<<dim3((NN + 63) / 64, 12), dim3(256), 0, stream>>>(
        z, params, flag, V16, qpb, qp16, kpb, diagK, stab);
    k_kp  <<<dim3(NN * NH / 64), dim3(256), 0, stream>>>(kpb, diagK, stab, kpsum, kp16);
    k_an  <<<dim3((NN * NH + 255) / 256), dim3(256), 0, stream>>>(qpb, kpsum, anb);
    k_edge<<<dim3(NE / 64), dim3(256), 0, stream>>>(ei, qp16, kp16, anb, din, lossp);
    // qp16/kp16 dead from here; Pkvs overlays them (stream-ordered)
    k_kvs <<<dim3(KVS_CHUNKS, NH, DH / KVS_DZ), dim3(320), 0, stream>>>(kpb, gum, V16, flag, Pkvs, Pksum);
    k_reduce<<<dim3((NH * KG * MF * DH + NH * KG * MF + 255) / 256), dim3(256), 0, stream>>>(
        Pkvs, Pksum, kvs, ksum);
    // zatt overwrites kpb/diagK/anb from here on (stream-ordered after their last readers)
    k_attn<<<dim3(NN / AT_NT), dim3(256), 0, stream>>>(qpb, kvs, ksum, zatt);
    k_conv<<<dim3(NN), dim3(256), 0, stream>>>(zatt, V16, csr, wedge, offn, din, params, out);
    k_loss<<<dim3(1), dim3(256), 0, stream>>>(lossp, out);
}